// Round 1
// baseline (9308.233 us; speedup 1.0000x reference)
//
#include <hip/hip_runtime.h>
#include <hip/hip_bf16.h>

// HAN_81801947119983 — round 0: correct fp32 baseline.
// B=64, D=40, S=50, E=200, H=128, C=10. N1=B*D=2560 word rows, T1=50.
// ws layout (floats): G1[M1*768] | low[M1*256] | proj[M1*128] | sent[2560*256]
//                     | Gs[2560*768] | high[2560*256] | projs[2560*128] | dvec[64*256]
// G cols: [0:256) fw gates, [256:384) fw cand, [384:640) bw gates, [640:768) bw cand.

__device__ __forceinline__ float fsigmoid(float x) { return 1.f / (1.f + __expf(-x)); }
__device__ __forceinline__ float ftanh(float x)    { float e = __expf(2.f * x); return 1.f - 2.f / (e + 1.f); }

// ---------------- GEMM: C[:,colOff:colOff+N] = act(A[M,K] @ W[K,N] + bias) ----------------
// M % 128 == 0, N in {128,256}, K % 8 == 0. 128x128 tile, 8x8 per thread.
__global__ __launch_bounds__(256) void gemm_bias(
    const float* __restrict__ A, const float* __restrict__ W,
    const float* __restrict__ bias, float* __restrict__ C,
    int M, int N, int K, int ldc, int colOff, int act)
{
    __shared__ float As[8][128];
    __shared__ float Bs[8][128];
    int tid = threadIdx.x;
    int bm = blockIdx.x, bn = blockIdx.y;
    int tx = tid & 15, ty = tid >> 4;
    int m0 = ty * 8, n0 = tx * 8;
    float acc[8][8];
#pragma unroll
    for (int i = 0; i < 8; ++i)
#pragma unroll
        for (int j = 0; j < 8; ++j) acc[i][j] = 0.f;

    const float* Ab = A + (size_t)bm * 128 * K;
    const float* Wb = W + bn * 128;
    int la_m = tid >> 1;            // 0..127
    int la_k = (tid & 1) * 4;       // 0 or 4
    int lb_k = tid >> 5;            // 0..7
    int lb_n = (tid & 31) * 4;      // 0..124

    for (int kk = 0; kk < K; kk += 8) {
        float4 av = *(const float4*)&Ab[(size_t)la_m * K + kk + la_k];
        float4 bv = *(const float4*)&Wb[(size_t)(kk + lb_k) * N + lb_n];
        __syncthreads();
        As[la_k + 0][la_m] = av.x;
        As[la_k + 1][la_m] = av.y;
        As[la_k + 2][la_m] = av.z;
        As[la_k + 3][la_m] = av.w;
        *(float4*)&Bs[lb_k][lb_n] = bv;
        __syncthreads();
#pragma unroll
        for (int k = 0; k < 8; ++k) {
            float4 a0 = *(const float4*)&As[k][m0];
            float4 a1 = *(const float4*)&As[k][m0 + 4];
            float4 b0 = *(const float4*)&Bs[k][n0];
            float4 b1 = *(const float4*)&Bs[k][n0 + 4];
            float aa[8] = {a0.x, a0.y, a0.z, a0.w, a1.x, a1.y, a1.z, a1.w};
            float bb[8] = {b0.x, b0.y, b0.z, b0.w, b1.x, b1.y, b1.z, b1.w};
#pragma unroll
            for (int i = 0; i < 8; ++i)
#pragma unroll
                for (int j = 0; j < 8; ++j) acc[i][j] += aa[i] * bb[j];
        }
    }
    // epilogue
#pragma unroll
    for (int i = 0; i < 8; ++i) {
        size_t row = (size_t)(bm * 128 + m0 + i) * ldc + colOff + bn * 128;
#pragma unroll
        for (int j = 0; j < 8; ++j) {
            float v = acc[i][j] + bias[bn * 128 + n0 + j];
            if (act) v = ftanh(v);
            C[row + n0 + j] = v;
        }
    }
}

// ---------------- word-level BiGRU: 16 rows/block, 50 steps ----------------
__global__ __launch_bounds__(256) void word_rnn(
    const float* __restrict__ G,     // [nRows*50, 768] chunk-local
    const float* __restrict__ wgf, const float* __restrict__ wcf,
    const float* __restrict__ wgb, const float* __restrict__ wcb,
    const int* __restrict__ slen,    // global
    float* __restrict__ low,         // [nRows*50, 256] chunk-local, zero-inited
    int rowOff)
{
    __shared__ float hb[2][16][128];
    __shared__ float rh[16][128];
    __shared__ float zt[16][128];
    __shared__ int Ls[16];
    int tid = threadIdx.x;
    int r0 = blockIdx.x * 16;
    for (int i = tid; i < 2 * 16 * 128; i += 256) (&hb[0][0][0])[i] = 0.f;
    if (tid < 16) Ls[tid] = slen[rowOff + r0 + tid];
    __syncthreads();

    int rg = tid >> 6, jg = tid & 63;    // phase A: 4 rows x 4 cols
    int rg2 = tid >> 5, jg2 = tid & 31;  // phase B: 2 rows x 4 cols
    int c0 = jg * 4, c1 = jg2 * 4;

    for (int t = 0; t < 50; ++t) {
        for (int dir = 0; dir < 2; ++dir) {
            const float* Wg = (dir ? wgb : wgf) + 200 * 256;  // h-part rows
            const float* Wc = (dir ? wcb : wcf) + 200 * 128;
            int offG = dir * 384;
            // ---- phase A: gates rz ----
            float4 acc[4];
#pragma unroll
            for (int i = 0; i < 4; ++i) {
                int r = rg * 4 + i;
                int L = Ls[r];
                int ti = dir ? ((t < L) ? (L - 1 - t) : 0) : t;
                acc[i] = *(const float4*)&G[((size_t)(r0 + r) * 50 + ti) * 768 + offG + c0];
            }
            for (int k = 0; k < 128; k += 4) {
                float4 w0 = *(const float4*)&Wg[(k + 0) * 256 + c0];
                float4 w1 = *(const float4*)&Wg[(k + 1) * 256 + c0];
                float4 w2 = *(const float4*)&Wg[(k + 2) * 256 + c0];
                float4 w3 = *(const float4*)&Wg[(k + 3) * 256 + c0];
#pragma unroll
                for (int i = 0; i < 4; ++i) {
                    float4 h4 = *(const float4*)&hb[dir][rg * 4 + i][k];
                    acc[i].x += h4.x * w0.x + h4.y * w1.x + h4.z * w2.x + h4.w * w3.x;
                    acc[i].y += h4.x * w0.y + h4.y * w1.y + h4.z * w2.y + h4.w * w3.y;
                    acc[i].z += h4.x * w0.z + h4.y * w1.z + h4.z * w2.z + h4.w * w3.z;
                    acc[i].w += h4.x * w0.w + h4.y * w1.w + h4.z * w2.w + h4.w * w3.w;
                }
            }
#pragma unroll
            for (int i = 0; i < 4; ++i) {
                int r = rg * 4 + i;
                float g[4] = {acc[i].x, acc[i].y, acc[i].z, acc[i].w};
#pragma unroll
                for (int j = 0; j < 4; ++j) {
                    int c = c0 + j;
                    float s = fsigmoid(g[j]);
                    if (c < 128) rh[r][c] = s * hb[dir][r][c];
                    else         zt[r][c - 128] = s;
                }
            }
            __syncthreads();
            // ---- phase B: candidate + h update ----
            float4 accB[2];
            int tIdxB[2]; bool vB[2];
#pragma unroll
            for (int i = 0; i < 2; ++i) {
                int r = rg2 * 2 + i;
                int L = Ls[r];
                vB[i] = (t < L);
                tIdxB[i] = dir ? (vB[i] ? (L - 1 - t) : 0) : t;
                accB[i] = *(const float4*)&G[((size_t)(r0 + r) * 50 + tIdxB[i]) * 768 + offG + 256 + c1];
            }
            for (int k = 0; k < 128; k += 4) {
                float4 w0 = *(const float4*)&Wc[(k + 0) * 128 + c1];
                float4 w1 = *(const float4*)&Wc[(k + 1) * 128 + c1];
                float4 w2 = *(const float4*)&Wc[(k + 2) * 128 + c1];
                float4 w3 = *(const float4*)&Wc[(k + 3) * 128 + c1];
#pragma unroll
                for (int i = 0; i < 2; ++i) {
                    float4 p4 = *(const float4*)&rh[rg2 * 2 + i][k];
                    accB[i].x += p4.x * w0.x + p4.y * w1.x + p4.z * w2.x + p4.w * w3.x;
                    accB[i].y += p4.x * w0.y + p4.y * w1.y + p4.z * w2.y + p4.w * w3.y;
                    accB[i].z += p4.x * w0.z + p4.y * w1.z + p4.z * w2.z + p4.w * w3.z;
                    accB[i].w += p4.x * w0.w + p4.y * w1.w + p4.z * w2.w + p4.w * w3.w;
                }
            }
#pragma unroll
            for (int i = 0; i < 2; ++i) {
                int r = rg2 * 2 + i;
                if (vB[i]) {
                    float4 cb;
                    cb.x = ftanh(accB[i].x); cb.y = ftanh(accB[i].y);
                    cb.z = ftanh(accB[i].z); cb.w = ftanh(accB[i].w);
                    float4 z4 = *(const float4*)&zt[r][c1];
                    float4 ho = *(const float4*)&hb[dir][r][c1];
                    float4 hn;
                    hn.x = z4.x * ho.x + (1.f - z4.x) * cb.x;
                    hn.y = z4.y * ho.y + (1.f - z4.y) * cb.y;
                    hn.z = z4.z * ho.z + (1.f - z4.z) * cb.z;
                    hn.w = z4.w * ho.w + (1.f - z4.w) * cb.w;
                    *(float4*)&hb[dir][r][c1] = hn;
                    *(float4*)&low[((size_t)(r0 + r) * 50 + tIdxB[i]) * 256 + dir * 128 + c1] = hn;
                }
            }
            __syncthreads();
        }
    }
}

// ---------------- sentence-level BiGRU: 128 blocks = 64 rows x 2 dirs, 1 wave ----------------
__global__ __launch_bounds__(64) void sent_rnn(
    const float* __restrict__ Gs,    // [2560, 768]
    const float* __restrict__ wgfh, const float* __restrict__ wcfh,
    const float* __restrict__ wgbh, const float* __restrict__ wcbh,
    const int* __restrict__ dlen,
    float* __restrict__ high)        // [2560, 256] zero-inited
{
    __shared__ float hv[128], rhv[128], zv[128];
    int b = blockIdx.x;
    int dir = b >> 6, n = b & 63;
    int tid = threadIdx.x;
    const float* Wg = (dir ? wgbh : wgfh) + 256 * 256;
    const float* Wc = (dir ? wcbh : wcfh) + 256 * 128;
    for (int i = tid; i < 128; i += 64) hv[i] = 0.f;
    int L = dlen[n];
    __syncthreads();
    int j0 = tid * 4;
    for (int t = 0; t < 40; ++t) {
        bool valid = (t < L);
        int ti = dir ? (valid ? (L - 1 - t) : 0) : t;
        const float* Grow = &Gs[((size_t)n * 40 + ti) * 768 + dir * 384];
        float4 acc = *(const float4*)&Grow[j0];
        for (int k = 0; k < 128; ++k) {
            float h = hv[k];
            float4 w = *(const float4*)&Wg[k * 256 + j0];
            acc.x += h * w.x; acc.y += h * w.y; acc.z += h * w.z; acc.w += h * w.w;
        }
        float4 s4;
        s4.x = fsigmoid(acc.x); s4.y = fsigmoid(acc.y);
        s4.z = fsigmoid(acc.z); s4.w = fsigmoid(acc.w);
        if (j0 < 128) {
            float4 h4 = *(const float4*)&hv[j0];
            float4 p; p.x = s4.x * h4.x; p.y = s4.y * h4.y; p.z = s4.z * h4.z; p.w = s4.w * h4.w;
            *(float4*)&rhv[j0] = p;
        } else {
            *(float4*)&zv[j0 - 128] = s4;
        }
        __syncthreads();
        if (tid < 32) {
            int j1 = tid * 4;
            float4 aB = *(const float4*)&Grow[256 + j1];
            for (int k = 0; k < 128; ++k) {
                float p = rhv[k];
                float4 w = *(const float4*)&Wc[k * 128 + j1];
                aB.x += p * w.x; aB.y += p * w.y; aB.z += p * w.z; aB.w += p * w.w;
            }
            float4 cb;
            cb.x = ftanh(aB.x); cb.y = ftanh(aB.y); cb.z = ftanh(aB.z); cb.w = ftanh(aB.w);
            float4 z4 = *(const float4*)&zv[j1];
            float4 ho = *(const float4*)&hv[j1];
            float4 hn;
            hn.x = z4.x * ho.x + (1.f - z4.x) * cb.x;
            hn.y = z4.y * ho.y + (1.f - z4.y) * cb.y;
            hn.z = z4.z * ho.z + (1.f - z4.z) * cb.z;
            hn.w = z4.w * ho.w + (1.f - z4.w) * cb.w;
            if (valid) {
                *(float4*)&hv[j1] = hn;
                *(float4*)&high[((size_t)n * 40 + ti) * 256 + dir * 128 + j1] = hn;
            }
        }
        __syncthreads();
    }
}

// ---------------- attention score/softmax/weighted-sum: 1 wave per row ----------------
__global__ __launch_bounds__(64) void attn_reduce(
    const float* __restrict__ proj,  // [n*T, 128], already tanh(out@Wa+ba)
    const float* __restrict__ outv,  // [n*T, 256]
    const float* __restrict__ u,     // [128]
    float* __restrict__ att_out,     // rows indexed (attRowOff+n)*T
    float* __restrict__ vec,         // [n, 256]
    int T, int attRowOff)
{
    int n = blockIdx.x, lane = threadIdx.x;
    float s = 0.f;
    if (lane < T) {
        const float4* p = (const float4*)(proj + ((size_t)n * T + lane) * 128);
        const float4* uu = (const float4*)u;
        for (int k = 0; k < 32; ++k) {
            float4 a = p[k], b = uu[k];
            s += a.x * b.x + a.y * b.y + a.z * b.z + a.w * b.w;
        }
    }
    float m = (lane < T) ? s : -3.402823466e38f;
    for (int o = 32; o > 0; o >>= 1) m = fmaxf(m, __shfl_xor(m, o));
    float e = (lane < T) ? __expf(s - m) : 0.f;
    float sum = e;
    for (int o = 32; o > 0; o >>= 1) sum += __shfl_xor(sum, o);
    float att = e / sum;
    if (lane < T) att_out[(size_t)(attRowOff + n) * T + lane] = att;
    float4 acc = {0.f, 0.f, 0.f, 0.f};
    for (int t = 0; t < T; ++t) {
        float a = __shfl(att, t);
        float4 o4 = *(const float4*)&outv[((size_t)n * T + t) * 256 + lane * 4];
        acc.x += a * o4.x; acc.y += a * o4.y; acc.z += a * o4.z; acc.w += a * o4.w;
    }
    *(float4*)&vec[(size_t)n * 256 + lane * 4] = acc;
}

// ---------------- head: logits, log-softmax, loss(+reg), predict, accuracy ----------------
__global__ __launch_bounds__(256) void head_kernel(
    const float* __restrict__ dvec, const float* __restrict__ wp, const float* __restrict__ bp,
    const int* __restrict__ y,
    const float* __restrict__ wa_l, const float* __restrict__ ba_l, const float* __restrict__ wa_h,
    const float* __restrict__ uw, const float* __restrict__ us,
    float* __restrict__ out)
{
    __shared__ float lg[64][10];
    __shared__ float red[256];
    int tid = threadIdx.x;
    for (int idx = tid; idx < 640; idx += 256) {
        int r = idx / 10, c = idx % 10;
        float a = bp[c];
        const float* dv = dvec + r * 256;
        for (int k = 0; k < 256; ++k) a += dv[k] * wp[k * 10 + c];
        lg[r][c] = a;
    }
    __syncthreads();
    float lossv = 0.f, corr = 0.f;
    if (tid < 64) {
        float m = lg[tid][0]; int arg = 0;
        for (int c = 1; c < 10; ++c) if (lg[tid][c] > m) { m = lg[tid][c]; arg = c; }
        float se = 0.f;
        for (int c = 0; c < 10; ++c) se += __expf(lg[tid][c] - m);
        float lse = m + __logf(se);
        int yy = y[tid];
        lossv = -(lg[tid][yy] - lse);
        corr = (yy == arg) ? 1.f : 0.f;
        out[1 + tid] = (float)arg;
    }
    float rs = 0.f;
    for (int i = tid; i < 32768; i += 256) {
        float v = wa_l[i]; rs += v * v;
        float w = wa_h[i]; rs += 2.f * w * w;
    }
    if (tid < 128) {
        float v1 = ba_l[tid], v2 = uw[tid], v3 = us[tid];
        rs += v1 * v1 + v2 * v2 + v3 * v3;
    }
    // reductions
    red[tid] = lossv; __syncthreads();
    for (int o = 128; o > 0; o >>= 1) { if (tid < o) red[tid] += red[tid + o]; __syncthreads(); }
    float totLoss = red[0]; __syncthreads();
    red[tid] = corr; __syncthreads();
    for (int o = 128; o > 0; o >>= 1) { if (tid < o) red[tid] += red[tid + o]; __syncthreads(); }
    float totCorr = red[0]; __syncthreads();
    red[tid] = rs; __syncthreads();
    for (int o = 128; o > 0; o >>= 1) { if (tid < o) red[tid] += red[tid + o]; __syncthreads(); }
    float totReg = red[0];
    if (tid == 0) {
        out[0] = totLoss / 64.f + 0.01f * totReg;
        out[65] = totCorr / 64.f;
    }
}

extern "C" void kernel_launch(void* const* d_in, const int* in_sizes, int n_in,
                              void* d_out, int out_size, void* d_ws, size_t ws_size,
                              hipStream_t stream)
{
    const float* X    = (const float*)d_in[0];
    const int*   y    = (const int*)d_in[1];
    const int*   slen = (const int*)d_in[2];
    const int*   dlen = (const int*)d_in[3];
    const float* wgf_l = (const float*)d_in[6];
    const float* bgf_l = (const float*)d_in[7];
    const float* wcf_l = (const float*)d_in[8];
    const float* bcf_l = (const float*)d_in[9];
    const float* wgb_l = (const float*)d_in[10];
    const float* bgb_l = (const float*)d_in[11];
    const float* wcb_l = (const float*)d_in[12];
    const float* bcb_l = (const float*)d_in[13];
    const float* wa_l  = (const float*)d_in[14];
    const float* ba_l  = (const float*)d_in[15];
    const float* wgf_h = (const float*)d_in[16];
    const float* bgf_h = (const float*)d_in[17];
    const float* wcf_h = (const float*)d_in[18];
    const float* bcf_h = (const float*)d_in[19];
    const float* wgb_h = (const float*)d_in[20];
    const float* bgb_h = (const float*)d_in[21];
    const float* wcb_h = (const float*)d_in[22];
    const float* bcb_h = (const float*)d_in[23];
    const float* wa_h  = (const float*)d_in[24];
    const float* ba_h  = (const float*)d_in[25];
    const float* uw    = (const float*)d_in[26];
    const float* us    = (const float*)d_in[27];
    const float* wp    = (const float*)d_in[28];
    const float* bp    = (const float*)d_in[29];
    float* out = (float*)d_out;

    // pick chunking so workspace fits: need = (M1*1152 + const) * 4 bytes
    int NCH = 1;
    while (NCH < 8) {
        size_t M1t = 128000ull / NCH;
        size_t needB = (M1t * 1152ull + 3620864ull) * 4ull;
        if (needB <= ws_size) break;
        NCH *= 2;
    }
    size_t nRows = 2560 / NCH;
    size_t M1 = nRows * 50;

    float* G1    = (float*)d_ws;
    float* low   = G1 + M1 * 768;
    float* proj  = low + M1 * 256;
    float* sent  = proj + M1 * 128;
    float* Gs    = sent + 655360;
    float* high  = Gs + 1966080;
    float* projs = high + 655360;
    float* dvec  = projs + 327680;

    for (int c = 0; c < NCH; ++c) {
        const float* Xc = X + (size_t)c * nRows * 50 * 200;
        hipMemsetAsync(low, 0, M1 * 256 * sizeof(float), stream);
        gemm_bias<<<dim3((int)(M1 / 128), 2), 256, 0, stream>>>(Xc, wgf_l, bgf_l, G1, (int)M1, 256, 200, 768, 0, 0);
        gemm_bias<<<dim3((int)(M1 / 128), 1), 256, 0, stream>>>(Xc, wcf_l, bcf_l, G1, (int)M1, 128, 200, 768, 256, 0);
        gemm_bias<<<dim3((int)(M1 / 128), 2), 256, 0, stream>>>(Xc, wgb_l, bgb_l, G1, (int)M1, 256, 200, 768, 384, 0);
        gemm_bias<<<dim3((int)(M1 / 128), 1), 256, 0, stream>>>(Xc, wcb_l, bcb_l, G1, (int)M1, 128, 200, 768, 640, 0);
        word_rnn<<<(int)(nRows / 16), 256, 0, stream>>>(G1, wgf_l, wcf_l, wgb_l, wcb_l, slen, low, (int)(c * nRows));
        gemm_bias<<<dim3((int)(M1 / 128), 1), 256, 0, stream>>>(low, wa_l, ba_l, proj, (int)M1, 128, 256, 128, 0, 1);
        attn_reduce<<<(int)nRows, 64, 0, stream>>>(proj, low, uw, out + 66, sent + (size_t)c * nRows * 256, 50, (int)(c * nRows));
    }
    hipMemsetAsync(high, 0, 2560ull * 256 * sizeof(float), stream);
    gemm_bias<<<dim3(20, 2), 256, 0, stream>>>(sent, wgf_h, bgf_h, Gs, 2560, 256, 256, 768, 0, 0);
    gemm_bias<<<dim3(20, 1), 256, 0, stream>>>(sent, wcf_h, bcf_h, Gs, 2560, 128, 256, 768, 256, 0);
    gemm_bias<<<dim3(20, 2), 256, 0, stream>>>(sent, wgb_h, bgb_h, Gs, 2560, 256, 256, 768, 384, 0);
    gemm_bias<<<dim3(20, 1), 256, 0, stream>>>(sent, wcb_h, bcb_h, Gs, 2560, 128, 256, 768, 640, 0);
    sent_rnn<<<128, 64, 0, stream>>>(Gs, wgf_h, wcf_h, wgb_h, wcb_h, dlen, high);
    gemm_bias<<<dim3(20, 1), 256, 0, stream>>>(high, wa_h, ba_h, projs, 2560, 128, 256, 128, 0, 1);
    attn_reduce<<<64, 64, 0, stream>>>(projs, high, us, out + 128066, dvec, 40, 0);
    head_kernel<<<1, 256, 0, stream>>>(dvec, wp, bp, y, wa_l, ba_l, wa_h, uw, us, out);
}

// Round 2
// 2600.400 us; speedup vs baseline: 3.5795x; 3.5795x over previous
//
#include <hip/hip_runtime.h>
#include <hip/hip_bf16.h>

// HAN_81801947119983 — round 2: fix word_rnn (occupancy + spills + conflicts), fuse X-GEMMs.
// B=64, D=40, S=50, E=200, H=128, C=10. N1=2560 word rows (T=50), 64 doc rows (T=40).
// G cols: [0:256) fw gates, [256:384) fw cand, [384:640) bw gates, [640:768) bw cand.

__device__ __forceinline__ float fsigmoid(float x) { return 1.f / (1.f + __expf(-x)); }
__device__ __forceinline__ float ftanh(float x)    { float e = __expf(2.f * x); return 1.f - 2.f / (e + 1.f); }

// ---------------- weight pack: W[E,768] = [wg_f.x | wc_f.x | wg_b.x | wc_b.x], bias[768] ----------------
__global__ __launch_bounds__(256) void pack_weights(
    const float* __restrict__ wg_f, const float* __restrict__ bg_f,
    const float* __restrict__ wc_f, const float* __restrict__ bc_f,
    const float* __restrict__ wg_b, const float* __restrict__ bg_b,
    const float* __restrict__ wc_b, const float* __restrict__ bc_b,
    float* __restrict__ W, float* __restrict__ bias, int E)
{
    int idx = blockIdx.x * 256 + threadIdx.x;
    if (idx < 768) {
        int c = idx; float v;
        if (c < 256) v = bg_f[c];
        else if (c < 384) v = bc_f[c - 256];
        else if (c < 640) v = bg_b[c - 384];
        else v = bc_b[c - 640];
        bias[c] = v;
    }
    if (idx >= E * 768) return;
    int k = idx / 768, c = idx - k * 768;
    float v;
    if (c < 256) v = wg_f[k * 256 + c];
    else if (c < 384) v = wc_f[k * 128 + (c - 256)];
    else if (c < 640) v = wg_b[k * 256 + (c - 384)];
    else v = wc_b[k * 128 + (c - 640)];
    W[idx] = v;
}

// ---------------- GEMM: C[:,colOff:colOff+N] = act(A[M,K] @ W[K,N] + bias) ----------------
// M % 128 == 0, N % 128 == 0, K % 8 == 0. 128x128 tile, 8x8 per thread.
__global__ __launch_bounds__(256) void gemm_bias(
    const float* __restrict__ A, const float* __restrict__ W,
    const float* __restrict__ bias, float* __restrict__ C,
    int M, int N, int K, int ldc, int colOff, int act)
{
    __shared__ float As[8][128];
    __shared__ float Bs[8][128];
    int tid = threadIdx.x;
    int bm = blockIdx.x, bn = blockIdx.y;
    int tx = tid & 15, ty = tid >> 4;
    int m0 = ty * 8, n0 = tx * 8;
    float acc[8][8];
#pragma unroll
    for (int i = 0; i < 8; ++i)
#pragma unroll
        for (int j = 0; j < 8; ++j) acc[i][j] = 0.f;

    const float* Ab = A + (size_t)bm * 128 * K;
    const float* Wb = W + bn * 128;
    int la_m = tid >> 1;            // 0..127
    int la_k = (tid & 1) * 4;       // 0 or 4
    int lb_k = tid >> 5;            // 0..7
    int lb_n = (tid & 31) * 4;      // 0..124

    for (int kk = 0; kk < K; kk += 8) {
        float4 av = *(const float4*)&Ab[(size_t)la_m * K + kk + la_k];
        float4 bv = *(const float4*)&Wb[(size_t)(kk + lb_k) * N + lb_n];
        __syncthreads();
        As[la_k + 0][la_m] = av.x;
        As[la_k + 1][la_m] = av.y;
        As[la_k + 2][la_m] = av.z;
        As[la_k + 3][la_m] = av.w;
        *(float4*)&Bs[lb_k][lb_n] = bv;
        __syncthreads();
#pragma unroll
        for (int k = 0; k < 8; ++k) {
            float4 a0 = *(const float4*)&As[k][m0];
            float4 a1 = *(const float4*)&As[k][m0 + 4];
            float4 b0 = *(const float4*)&Bs[k][n0];
            float4 b1 = *(const float4*)&Bs[k][n0 + 4];
            float aa[8] = {a0.x, a0.y, a0.z, a0.w, a1.x, a1.y, a1.z, a1.w};
            float bb[8] = {b0.x, b0.y, b0.z, b0.w, b1.x, b1.y, b1.z, b1.w};
#pragma unroll
            for (int i = 0; i < 8; ++i)
#pragma unroll
                for (int j = 0; j < 8; ++j) acc[i][j] += aa[i] * bb[j];
        }
    }
#pragma unroll
    for (int i = 0; i < 8; ++i) {
        size_t row = (size_t)(bm * 128 + m0 + i) * ldc + colOff + bn * 128;
#pragma unroll
        for (int j = 0; j < 8; ++j) {
            float v = acc[i][j] + bias[bn * 128 + n0 + j];
            if (act) v = ftanh(v);
            C[row + n0 + j] = v;
        }
    }
}

// ---------------- generic BiGRU recurrence: 8 rows x 1 dir per block, 4 waves ----------------
// Waves split (K-half x row-half). State hb/rh/zt in LDS as [hidx][row] so the
// K-loop reads are wave-uniform b128 broadcasts (conflict-free) and elementwise
// phases are lane-consecutive float4 (conflict-free). Partials red[kh][r][c]:
// float4 writes conflict-free, reduce reads 2-way (free).
__global__ __launch_bounds__(256) void bigru_rnn(
    const float* __restrict__ G,      // [nRows*T, 768] chunk-local
    const float* __restrict__ WgF, const float* __restrict__ WcF,  // h-part [128,256]/[128,128]
    const float* __restrict__ WgB, const float* __restrict__ WcB,
    const int* __restrict__ lens,     // global
    float* __restrict__ outbuf,       // [nRows*T, 256] zero-init
    int rowOff, int T)
{
    __shared__ float hb[128][8];
    __shared__ float rh[128][8];
    __shared__ float zt[128][8];
    __shared__ float red[2][8][256];
    __shared__ int Ls[8];

    int tid = threadIdx.x;
    int dir = blockIdx.x & 1;
    int rg0 = (blockIdx.x >> 1) * 8;
    const float* Wg = dir ? WgB : WgF;
    const float* Wc = dir ? WcB : WcF;
    for (int i = tid; i < 128 * 8; i += 256) (&hb[0][0])[i] = 0.f;
    if (tid < 8) Ls[tid] = lens[rowOff + rg0 + tid];
    __syncthreads();

    int lane = tid & 63;
    int w = tid >> 6;
    int kh = w >> 1;                  // K-half: k in [kh*64, kh*64+64)
    int r2 = (w & 1) * 4;             // row-half: rows r2..r2+3
    int k0 = kh * 64;
    int cA = lane * 4;                // phase-A cols (0..252)
    int cB = lane * 2;                // phase-B cols (0..126)
    int hc = tid >> 1;                // reduce col 0..127
    int r4 = (tid & 1) * 4;           // reduce rows r4..r4+3
    const int goff = dir * 384;

    for (int t = 0; t < T; ++t) {
        // ---- phase A: gate partials (8 rows x 256 cols, K=128) ----
        {
            float acc[4][4];
#pragma unroll
            for (int i = 0; i < 4; ++i)
#pragma unroll
                for (int j = 0; j < 4; ++j) acc[i][j] = 0.f;
            const float* wp = Wg + (size_t)k0 * 256 + cA;
#pragma unroll 4
            for (int k = 0; k < 64; ++k) {
                float4 wv = *(const float4*)(wp + (size_t)k * 256);
                float4 hv = *(const float4*)&hb[k0 + k][r2];
                float hr[4] = {hv.x, hv.y, hv.z, hv.w};
#pragma unroll
                for (int i = 0; i < 4; ++i) {
                    acc[i][0] += hr[i] * wv.x;
                    acc[i][1] += hr[i] * wv.y;
                    acc[i][2] += hr[i] * wv.z;
                    acc[i][3] += hr[i] * wv.w;
                }
            }
#pragma unroll
            for (int i = 0; i < 4; ++i)
                *(float4*)&red[kh][r2 + i][cA] = make_float4(acc[i][0], acc[i][1], acc[i][2], acc[i][3]);
        }
        __syncthreads();
        // ---- reduce A: gates = G + partials; rh = sigmoid(r)*h; zt = sigmoid(z) ----
        {
            float hbv[4]; *(float4*)hbv = *(const float4*)&hb[hc][r4];
            float rhv[4], ztv[4];
#pragma unroll
            for (int i = 0; i < 4; ++i) {
                int r = r4 + i;
                int L = Ls[r];
                int ti = dir ? ((t < L) ? (L - 1 - t) : t) : t;
                const float* grow = &G[((size_t)(rg0 + r) * T + ti) * 768 + goff];
                float gr = red[0][r][hc] + red[1][r][hc] + grow[hc];
                float gz = red[0][r][128 + hc] + red[1][r][128 + hc] + grow[128 + hc];
                rhv[i] = fsigmoid(gr) * hbv[i];
                ztv[i] = fsigmoid(gz);
            }
            *(float4*)&rh[hc][r4] = *(float4*)rhv;
            *(float4*)&zt[hc][r4] = *(float4*)ztv;
        }
        __syncthreads();
        // ---- phase B: candidate partials (8 rows x 128 cols, K=128) ----
        {
            float acc[4][2];
#pragma unroll
            for (int i = 0; i < 4; ++i) { acc[i][0] = 0.f; acc[i][1] = 0.f; }
            const float* wp = Wc + (size_t)k0 * 128 + cB;
#pragma unroll 4
            for (int k = 0; k < 64; ++k) {
                float2 wv = *(const float2*)(wp + (size_t)k * 128);
                float4 rv = *(const float4*)&rh[k0 + k][r2];
                float rr[4] = {rv.x, rv.y, rv.z, rv.w};
#pragma unroll
                for (int i = 0; i < 4; ++i) {
                    acc[i][0] += rr[i] * wv.x;
                    acc[i][1] += rr[i] * wv.y;
                }
            }
#pragma unroll
            for (int i = 0; i < 4; ++i)
                *(float2*)&red[kh][r2 + i][cB] = make_float2(acc[i][0], acc[i][1]);
        }
        __syncthreads();
        // ---- reduce B: cand = tanh(G + partials); h' = z*h + (1-z)*cand (masked) ----
        {
            float hbv[4]; *(float4*)hbv = *(const float4*)&hb[hc][r4];
            float ztv[4]; *(float4*)ztv = *(const float4*)&zt[hc][r4];
            float hn[4]; int ti4[4]; bool val[4];
#pragma unroll
            for (int i = 0; i < 4; ++i) {
                int r = r4 + i;
                int L = Ls[r];
                val[i] = (t < L);
                int ti = dir ? (val[i] ? (L - 1 - t) : t) : t;
                ti4[i] = ti;
                const float* grow = &G[((size_t)(rg0 + r) * T + ti) * 768 + goff];
                float cv = red[0][r][hc] + red[1][r][hc] + grow[256 + hc];
                float cd = ftanh(cv);
                float h = hbv[i], z = ztv[i];
                hn[i] = val[i] ? (z * h + (1.f - z) * cd) : h;
            }
            *(float4*)&hb[hc][r4] = *(float4*)hn;
#pragma unroll
            for (int i = 0; i < 4; ++i)
                if (val[i])
                    outbuf[((size_t)(rg0 + r4 + i) * T + ti4[i]) * 256 + dir * 128 + hc] = hn[i];
        }
        __syncthreads();
    }
}

// ---------------- attention score/softmax/weighted-sum: 1 wave per row ----------------
__global__ __launch_bounds__(64) void attn_reduce(
    const float* __restrict__ proj,  // [n*T, 128], already tanh(out@Wa+ba)
    const float* __restrict__ outv,  // [n*T, 256]
    const float* __restrict__ u,     // [128]
    float* __restrict__ att_out,     // rows indexed (attRowOff+n)*T
    float* __restrict__ vec,         // [n, 256]
    int T, int attRowOff)
{
    int n = blockIdx.x, lane = threadIdx.x;
    float s = 0.f;
    if (lane < T) {
        const float4* p = (const float4*)(proj + ((size_t)n * T + lane) * 128);
        const float4* uu = (const float4*)u;
        for (int k = 0; k < 32; ++k) {
            float4 a = p[k], b = uu[k];
            s += a.x * b.x + a.y * b.y + a.z * b.z + a.w * b.w;
        }
    }
    float m = (lane < T) ? s : -3.402823466e38f;
    for (int o = 32; o > 0; o >>= 1) m = fmaxf(m, __shfl_xor(m, o));
    float e = (lane < T) ? __expf(s - m) : 0.f;
    float sum = e;
    for (int o = 32; o > 0; o >>= 1) sum += __shfl_xor(sum, o);
    float att = e / sum;
    if (lane < T) att_out[(size_t)(attRowOff + n) * T + lane] = att;
    float4 acc = {0.f, 0.f, 0.f, 0.f};
    for (int t = 0; t < T; ++t) {
        float a = __shfl(att, t);
        float4 o4 = *(const float4*)&outv[((size_t)n * T + t) * 256 + lane * 4];
        acc.x += a * o4.x; acc.y += a * o4.y; acc.z += a * o4.z; acc.w += a * o4.w;
    }
    *(float4*)&vec[(size_t)n * 256 + lane * 4] = acc;
}

// ---------------- head: logits, log-softmax, loss(+reg), predict, accuracy ----------------
__global__ __launch_bounds__(256) void head_kernel(
    const float* __restrict__ dvec, const float* __restrict__ wp, const float* __restrict__ bp,
    const int* __restrict__ y,
    const float* __restrict__ wa_l, const float* __restrict__ ba_l, const float* __restrict__ wa_h,
    const float* __restrict__ uw, const float* __restrict__ us,
    float* __restrict__ out)
{
    __shared__ float lg[64][10];
    __shared__ float red[256];
    int tid = threadIdx.x;
    for (int idx = tid; idx < 640; idx += 256) {
        int r = idx / 10, c = idx % 10;
        float a = bp[c];
        const float* dv = dvec + r * 256;
        for (int k = 0; k < 256; ++k) a += dv[k] * wp[k * 10 + c];
        lg[r][c] = a;
    }
    __syncthreads();
    float lossv = 0.f, corr = 0.f;
    if (tid < 64) {
        float m = lg[tid][0]; int arg = 0;
        for (int c = 1; c < 10; ++c) if (lg[tid][c] > m) { m = lg[tid][c]; arg = c; }
        float se = 0.f;
        for (int c = 0; c < 10; ++c) se += __expf(lg[tid][c] - m);
        float lse = m + __logf(se);
        int yy = y[tid];
        lossv = -(lg[tid][yy] - lse);
        corr = (yy == arg) ? 1.f : 0.f;
        out[1 + tid] = (float)arg;
    }
    float rs = 0.f;
    for (int i = tid; i < 32768; i += 256) {
        float v = wa_l[i]; rs += v * v;
        float w = wa_h[i]; rs += 2.f * w * w;
    }
    if (tid < 128) {
        float v1 = ba_l[tid], v2 = uw[tid], v3 = us[tid];
        rs += v1 * v1 + v2 * v2 + v3 * v3;
    }
    red[tid] = lossv; __syncthreads();
    for (int o = 128; o > 0; o >>= 1) { if (tid < o) red[tid] += red[tid + o]; __syncthreads(); }
    float totLoss = red[0]; __syncthreads();
    red[tid] = corr; __syncthreads();
    for (int o = 128; o > 0; o >>= 1) { if (tid < o) red[tid] += red[tid + o]; __syncthreads(); }
    float totCorr = red[0]; __syncthreads();
    red[tid] = rs; __syncthreads();
    for (int o = 128; o > 0; o >>= 1) { if (tid < o) red[tid] += red[tid + o]; __syncthreads(); }
    float totReg = red[0];
    if (tid == 0) {
        out[0] = totLoss / 64.f + 0.01f * totReg;
        out[65] = totCorr / 64.f;
    }
}

extern "C" void kernel_launch(void* const* d_in, const int* in_sizes, int n_in,
                              void* d_out, int out_size, void* d_ws, size_t ws_size,
                              hipStream_t stream)
{
    const float* X    = (const float*)d_in[0];
    const int*   y    = (const int*)d_in[1];
    const int*   slen = (const int*)d_in[2];
    const int*   dlen = (const int*)d_in[3];
    const float* wgf_l = (const float*)d_in[6];
    const float* bgf_l = (const float*)d_in[7];
    const float* wcf_l = (const float*)d_in[8];
    const float* bcf_l = (const float*)d_in[9];
    const float* wgb_l = (const float*)d_in[10];
    const float* bgb_l = (const float*)d_in[11];
    const float* wcb_l = (const float*)d_in[12];
    const float* bcb_l = (const float*)d_in[13];
    const float* wa_l  = (const float*)d_in[14];
    const float* ba_l  = (const float*)d_in[15];
    const float* wgf_h = (const float*)d_in[16];
    const float* bgf_h = (const float*)d_in[17];
    const float* wcf_h = (const float*)d_in[18];
    const float* bcf_h = (const float*)d_in[19];
    const float* wgb_h = (const float*)d_in[20];
    const float* bgb_h = (const float*)d_in[21];
    const float* wcb_h = (const float*)d_in[22];
    const float* bcb_h = (const float*)d_in[23];
    const float* wa_h  = (const float*)d_in[24];
    const float* ba_h  = (const float*)d_in[25];
    const float* uw    = (const float*)d_in[26];
    const float* us    = (const float*)d_in[27];
    const float* wp    = (const float*)d_in[28];
    const float* bp    = (const float*)d_in[29];
    float* out = (float*)d_out;

    // workspace fit: need = (M1*1152 + 4,000,000) * 4 bytes
    int NCH = 1;
    while (NCH < 8) {
        size_t M1t = 128000ull / NCH;
        size_t needB = (M1t * 1152ull + 4000000ull) * 4ull;
        if (needB <= ws_size) break;
        NCH *= 2;
    }
    size_t nRows = 2560 / NCH;
    size_t M1 = nRows * 50;

    float* G1     = (float*)d_ws;
    float* low    = G1 + M1 * 768;
    float* proj   = low + M1 * 256;
    float* sent   = proj + M1 * 128;
    float* Gs     = sent + 655360;
    float* high   = Gs + 1966080;
    float* projs  = high + 655360;
    float* dvec   = projs + 327680;
    float* packWl = dvec + 16384;
    float* packBl = packWl + 153600;
    float* packWh = packBl + 768;
    float* packBh = packWh + 196608;

    // pack fused projection weights (both levels)
    pack_weights<<<600, 256, 0, stream>>>(wgf_l, bgf_l, wcf_l, bcf_l, wgb_l, bgb_l, wcb_l, bcb_l,
                                          packWl, packBl, 200);
    pack_weights<<<768, 256, 0, stream>>>(wgf_h, bgf_h, wcf_h, bcf_h, wgb_h, bgb_h, wcb_h, bcb_h,
                                          packWh, packBh, 256);

    for (int c = 0; c < NCH; ++c) {
        const float* Xc = X + (size_t)c * nRows * 50 * 200;
        hipMemsetAsync(low, 0, M1 * 256 * sizeof(float), stream);
        gemm_bias<<<dim3((int)(M1 / 128), 6), 256, 0, stream>>>(Xc, packWl, packBl, G1, (int)M1, 768, 200, 768, 0, 0);
        bigru_rnn<<<(int)(nRows / 8) * 2, 256, 0, stream>>>(G1,
            wgf_l + 200 * 256, wcf_l + 200 * 128, wgb_l + 200 * 256, wcb_l + 200 * 128,
            slen, low, (int)(c * nRows), 50);
        gemm_bias<<<dim3((int)(M1 / 128), 1), 256, 0, stream>>>(low, wa_l, ba_l, proj, (int)M1, 128, 256, 128, 0, 1);
        attn_reduce<<<(int)nRows, 64, 0, stream>>>(proj, low, uw, out + 66, sent + (size_t)c * nRows * 256, 50, (int)(c * nRows));
    }
    hipMemsetAsync(high, 0, 2560ull * 256 * sizeof(float), stream);
    gemm_bias<<<dim3(20, 6), 256, 0, stream>>>(sent, packWh, packBh, Gs, 2560, 768, 256, 768, 0, 0);
    bigru_rnn<<<16, 256, 0, stream>>>(Gs,
        wgf_h + 256 * 256, wcf_h + 256 * 128, wgb_h + 256 * 256, wcb_h + 256 * 128,
        dlen, high, 0, 40);
    gemm_bias<<<dim3(20, 1), 256, 0, stream>>>(high, wa_h, ba_h, projs, 2560, 128, 256, 128, 0, 1);
    attn_reduce<<<64, 64, 0, stream>>>(projs, high, us, out + 128066, dvec, 40, 0);
    head_kernel<<<1, 256, 0, stream>>>(dvec, wp, bp, y, wa_l, ba_l, wa_h, uw, us, out);
}

// Round 3
// 2217.380 us; speedup vs baseline: 4.1979x; 1.1727x over previous
//
#include <hip/hip_runtime.h>
#include <hip/hip_bf16.h>

// HAN_81801947119983 — round 3: split-bf16 MFMA GEMMs with fragment-order prepacking.
// B=64, D=40, S=50, E=200, H=128, C=10. N1=2560 word rows (T=50), 64 doc rows (T=40).
// G cols: [0:256) fw gates, [256:384) fw cand, [384:640) bw gates, [640:768) bw cand.
// MFMA 16x16x32 bf16 layouts (HW-verified per guide):
//   A frag: lane holds A[m=lane&15][k=quad*8+j], j=0..7 (one contiguous 16B).
//   B frag: lane holds B[k=quad*8+j][n=lane&15].
//   C/D:    col=lane&15, row=quad*4+reg.
// Pack layout (uint4 index): ((tile16*KC + kc)*4 + quad)*16 + (lane&15) — wave's frag
// load = 1KB contiguous, so the GEMM needs no LDS and no barriers.

typedef __attribute__((ext_vector_type(8))) short short8;
typedef __attribute__((ext_vector_type(4))) float f32x4;

__device__ __forceinline__ float fsigmoid(float x) { return 1.f / (1.f + __expf(-x)); }
__device__ __forceinline__ float ftanh(float x)    { float e = __expf(2.f * x); return 1.f - 2.f / (e + 1.f); }

__device__ __forceinline__ unsigned short f2bf(float x) {
    unsigned int u = __builtin_bit_cast(unsigned int, x);
    u += 0x7fffu + ((u >> 16) & 1u);
    return (unsigned short)(u >> 16);
}
__device__ __forceinline__ float bf2f(unsigned short h) {
    unsigned int u = ((unsigned int)h) << 16;
    return __builtin_bit_cast(float, u);
}
__device__ __forceinline__ uint4 pack8(const unsigned short* v) {
    uint4 r;
    r.x = (unsigned int)v[0] | ((unsigned int)v[1] << 16);
    r.y = (unsigned int)v[2] | ((unsigned int)v[3] << 16);
    r.z = (unsigned int)v[4] | ((unsigned int)v[5] << 16);
    r.w = (unsigned int)v[6] | ((unsigned int)v[7] << 16);
    return r;
}

// ---------------- weight concat: W[E,768] = [wg_f | wc_f | wg_b | wc_b], bias[768] ----------------
__global__ __launch_bounds__(256) void pack_weights(
    const float* __restrict__ wg_f, const float* __restrict__ bg_f,
    const float* __restrict__ wc_f, const float* __restrict__ bc_f,
    const float* __restrict__ wg_b, const float* __restrict__ bg_b,
    const float* __restrict__ wc_b, const float* __restrict__ bc_b,
    float* __restrict__ W, float* __restrict__ bias, int E)
{
    int idx = blockIdx.x * 256 + threadIdx.x;
    if (idx < 768) {
        int c = idx; float v;
        if (c < 256) v = bg_f[c];
        else if (c < 384) v = bc_f[c - 256];
        else if (c < 640) v = bg_b[c - 384];
        else v = bc_b[c - 640];
        bias[c] = v;
    }
    if (idx >= E * 768) return;
    int k = idx / 768, c = idx - k * 768;
    float v;
    if (c < 256) v = wg_f[k * 256 + c];
    else if (c < 384) v = wc_f[k * 128 + (c - 256)];
    else if (c < 640) v = wg_b[k * 256 + (c - 384)];
    else v = wc_b[k * 128 + (c - 640)];
    W[idx] = v;
}

// ---------------- pack A (row-major [Mr x Ks] fp32) into frag-order hi/lo bf16 ----------------
__global__ __launch_bounds__(256) void pack_a_frag(
    const float* __restrict__ src, uint4* __restrict__ dstH, uint4* __restrict__ dstL,
    int Mr16, int KC, int Ks)
{
    int idx = blockIdx.x * 256 + threadIdx.x;
    if (idx >= Mr16 * KC * 64) return;
    int lane = idx & 63;
    int g = idx >> 6;
    int mb = g / KC, kc = g - mb * KC;
    int m = lane & 15, quad = lane >> 4;
    int row = mb * 16 + m;
    int k0 = kc * 32 + quad * 8;
    const float* s = src + (size_t)row * Ks;
    unsigned short hi[8], lo[8];
#pragma unroll
    for (int j = 0; j < 8; ++j) {
        float x = (k0 + j < Ks) ? s[k0 + j] : 0.f;
        unsigned short h = f2bf(x);
        hi[j] = h;
        lo[j] = f2bf(x - bf2f(h));
    }
    dstH[idx] = pack8(hi);
    dstL[idx] = pack8(lo);
}

// ---------------- pack W (row-major [Ks x N] fp32) into frag-order hi/lo bf16 ----------------
__global__ __launch_bounds__(256) void pack_w_frag(
    const float* __restrict__ src, uint4* __restrict__ dstH, uint4* __restrict__ dstL,
    int N16, int KC, int Ks, int N)
{
    int idx = blockIdx.x * 256 + threadIdx.x;
    if (idx >= N16 * KC * 64) return;
    int lane = idx & 63;
    int g = idx >> 6;
    int nb = g / KC, kc = g - nb * KC;
    int m = lane & 15, quad = lane >> 4;
    int n = nb * 16 + m;
    int k0 = kc * 32 + quad * 8;
    unsigned short hi[8], lo[8];
#pragma unroll
    for (int j = 0; j < 8; ++j) {
        float x = (k0 + j < Ks) ? src[(size_t)(k0 + j) * N + n] : 0.f;
        unsigned short h = f2bf(x);
        hi[j] = h;
        lo[j] = f2bf(x - bf2f(h));
    }
    dstH[idx] = pack8(hi);
    dstL[idx] = pack8(lo);
}

// ---------------- MFMA GEMM: C = act(A @ W + bias), split-bf16 3-product ----------------
// grid (M/128, N/128), 256 thr = 4 waves in 2x2; wave tile 64x64 = 4x4 MFMA tiles.
// No LDS, no barriers: A/B frags are contiguous 1KB wave loads from the packs.
__global__ __launch_bounds__(256) void mfma_gemm(
    const uint4* __restrict__ Ah, const uint4* __restrict__ Al,
    const uint4* __restrict__ Bh, const uint4* __restrict__ Bl,
    const float* __restrict__ bias, float* __restrict__ C,
    int KC, int ldc, int act)
{
    int tid = threadIdx.x;
    int lane = tid & 63;
    int w = tid >> 6;
    int wm = w >> 1, wn = w & 1;
    int quad = lane >> 4, m = lane & 15;
    int bm = blockIdx.x, bn = blockIdx.y;
    f32x4 acc[4][4];
#pragma unroll
    for (int i = 0; i < 4; ++i)
#pragma unroll
        for (int j = 0; j < 4; ++j) acc[i][j] = (f32x4){0.f, 0.f, 0.f, 0.f};

    size_t aBase[4], bBase[4];
#pragma unroll
    for (int i = 0; i < 4; ++i) {
        aBase[i] = ((size_t)(bm * 8 + wm * 4 + i) * KC) * 64 + quad * 16 + m;
        bBase[i] = ((size_t)(bn * 8 + wn * 4 + i) * KC) * 64 + quad * 16 + m;
    }
    for (int kc = 0; kc < KC; ++kc) {
        short8 ah[4], al[4], bh[4], bl[4];
#pragma unroll
        for (int i = 0; i < 4; ++i) {
            ah[i] = __builtin_bit_cast(short8, Ah[aBase[i]]);
            al[i] = __builtin_bit_cast(short8, Al[aBase[i]]);
            bh[i] = __builtin_bit_cast(short8, Bh[bBase[i]]);
            bl[i] = __builtin_bit_cast(short8, Bl[bBase[i]]);
            aBase[i] += 64; bBase[i] += 64;
        }
#pragma unroll
        for (int i = 0; i < 4; ++i)
#pragma unroll
            for (int j = 0; j < 4; ++j) {
                acc[i][j] = __builtin_amdgcn_mfma_f32_16x16x32_bf16(ah[i], bh[j], acc[i][j], 0, 0, 0);
                acc[i][j] = __builtin_amdgcn_mfma_f32_16x16x32_bf16(ah[i], bl[j], acc[i][j], 0, 0, 0);
                acc[i][j] = __builtin_amdgcn_mfma_f32_16x16x32_bf16(al[i], bh[j], acc[i][j], 0, 0, 0);
            }
    }
#pragma unroll
    for (int i = 0; i < 4; ++i) {
        int row0 = bm * 128 + wm * 64 + i * 16 + quad * 4;
#pragma unroll
        for (int j = 0; j < 4; ++j) {
            int col = bn * 128 + wn * 64 + j * 16 + m;
            float b = bias[col];
#pragma unroll
            for (int r = 0; r < 4; ++r) {
                float v = acc[i][j][r] + b;
                if (act) v = ftanh(v);
                C[(size_t)(row0 + r) * ldc + col] = v;
            }
        }
    }
}

// ---------------- generic BiGRU recurrence: 8 rows x 1 dir per block, 4 waves ----------------
__global__ __launch_bounds__(256) void bigru_rnn(
    const float* __restrict__ G,      // [nRows*T, 768] chunk-local
    const float* __restrict__ WgF, const float* __restrict__ WcF,  // h-part [128,256]/[128,128]
    const float* __restrict__ WgB, const float* __restrict__ WcB,
    const int* __restrict__ lens,     // global
    float* __restrict__ outbuf,       // [nRows*T, 256] zero-init
    int rowOff, int T)
{
    __shared__ float hb[128][8];
    __shared__ float rh[128][8];
    __shared__ float zt[128][8];
    __shared__ float red[2][8][256];
    __shared__ int Ls[8];

    int tid = threadIdx.x;
    int dir = blockIdx.x & 1;
    int rg0 = (blockIdx.x >> 1) * 8;
    const float* Wg = dir ? WgB : WgF;
    const float* Wc = dir ? WcB : WcF;
    for (int i = tid; i < 128 * 8; i += 256) (&hb[0][0])[i] = 0.f;
    if (tid < 8) Ls[tid] = lens[rowOff + rg0 + tid];
    __syncthreads();

    int lane = tid & 63;
    int w = tid >> 6;
    int kh = w >> 1;
    int r2 = (w & 1) * 4;
    int k0 = kh * 64;
    int cA = lane * 4;
    int cB = lane * 2;
    int hc = tid >> 1;
    int r4 = (tid & 1) * 4;
    const int goff = dir * 384;

    for (int t = 0; t < T; ++t) {
        {
            float acc[4][4];
#pragma unroll
            for (int i = 0; i < 4; ++i)
#pragma unroll
                for (int j = 0; j < 4; ++j) acc[i][j] = 0.f;
            const float* wp = Wg + (size_t)k0 * 256 + cA;
#pragma unroll 4
            for (int k = 0; k < 64; ++k) {
                float4 wv = *(const float4*)(wp + (size_t)k * 256);
                float4 hv = *(const float4*)&hb[k0 + k][r2];
                float hr[4] = {hv.x, hv.y, hv.z, hv.w};
#pragma unroll
                for (int i = 0; i < 4; ++i) {
                    acc[i][0] += hr[i] * wv.x;
                    acc[i][1] += hr[i] * wv.y;
                    acc[i][2] += hr[i] * wv.z;
                    acc[i][3] += hr[i] * wv.w;
                }
            }
#pragma unroll
            for (int i = 0; i < 4; ++i)
                *(float4*)&red[kh][r2 + i][cA] = make_float4(acc[i][0], acc[i][1], acc[i][2], acc[i][3]);
        }
        __syncthreads();
        {
            float hbv[4]; *(float4*)hbv = *(const float4*)&hb[hc][r4];
            float rhv[4], ztv[4];
#pragma unroll
            for (int i = 0; i < 4; ++i) {
                int r = r4 + i;
                int L = Ls[r];
                int ti = dir ? ((t < L) ? (L - 1 - t) : t) : t;
                const float* grow = &G[((size_t)(rg0 + r) * T + ti) * 768 + goff];
                float gr = red[0][r][hc] + red[1][r][hc] + grow[hc];
                float gz = red[0][r][128 + hc] + red[1][r][128 + hc] + grow[128 + hc];
                rhv[i] = fsigmoid(gr) * hbv[i];
                ztv[i] = fsigmoid(gz);
            }
            *(float4*)&rh[hc][r4] = *(float4*)rhv;
            *(float4*)&zt[hc][r4] = *(float4*)ztv;
        }
        __syncthreads();
        {
            float acc[4][2];
#pragma unroll
            for (int i = 0; i < 4; ++i) { acc[i][0] = 0.f; acc[i][1] = 0.f; }
            const float* wp = Wc + (size_t)k0 * 128 + cB;
#pragma unroll 4
            for (int k = 0; k < 64; ++k) {
                float2 wv = *(const float2*)(wp + (size_t)k * 128);
                float4 rv = *(const float4*)&rh[k0 + k][r2];
                float rr[4] = {rv.x, rv.y, rv.z, rv.w};
#pragma unroll
                for (int i = 0; i < 4; ++i) {
                    acc[i][0] += rr[i] * wv.x;
                    acc[i][1] += rr[i] * wv.y;
                }
            }
#pragma unroll
            for (int i = 0; i < 4; ++i)
                *(float2*)&red[kh][r2 + i][cB] = make_float2(acc[i][0], acc[i][1]);
        }
        __syncthreads();
        {
            float hbv[4]; *(float4*)hbv = *(const float4*)&hb[hc][r4];
            float ztv[4]; *(float4*)ztv = *(const float4*)&zt[hc][r4];
            float hn[4]; int ti4[4]; bool val[4];
#pragma unroll
            for (int i = 0; i < 4; ++i) {
                int r = r4 + i;
                int L = Ls[r];
                val[i] = (t < L);
                int ti = dir ? (val[i] ? (L - 1 - t) : t) : t;
                ti4[i] = ti;
                const float* grow = &G[((size_t)(rg0 + r) * T + ti) * 768 + goff];
                float cv = red[0][r][hc] + red[1][r][hc] + grow[256 + hc];
                float cd = ftanh(cv);
                float h = hbv[i], z = ztv[i];
                hn[i] = val[i] ? (z * h + (1.f - z) * cd) : h;
            }
            *(float4*)&hb[hc][r4] = *(float4*)hn;
#pragma unroll
            for (int i = 0; i < 4; ++i)
                if (val[i])
                    outbuf[((size_t)(rg0 + r4 + i) * T + ti4[i]) * 256 + dir * 128 + hc] = hn[i];
        }
        __syncthreads();
    }
}

// ---------------- attention score/softmax/weighted-sum: 1 wave per row ----------------
__global__ __launch_bounds__(64) void attn_reduce(
    const float* __restrict__ proj,  // [n*T, 128], already tanh(out@Wa+ba)
    const float* __restrict__ outv,  // [n*T, 256]
    const float* __restrict__ u,     // [128]
    float* __restrict__ att_out,     // rows indexed (attRowOff+n)*T
    float* __restrict__ vec,         // [n, 256]
    int T, int attRowOff)
{
    int n = blockIdx.x, lane = threadIdx.x;
    float s = 0.f;
    if (lane < T) {
        const float4* p = (const float4*)(proj + ((size_t)n * T + lane) * 128);
        const float4* uu = (const float4*)u;
        for (int k = 0; k < 32; ++k) {
            float4 a = p[k], b = uu[k];
            s += a.x * b.x + a.y * b.y + a.z * b.z + a.w * b.w;
        }
    }
    float m = (lane < T) ? s : -3.402823466e38f;
    for (int o = 32; o > 0; o >>= 1) m = fmaxf(m, __shfl_xor(m, o));
    float e = (lane < T) ? __expf(s - m) : 0.f;
    float sum = e;
    for (int o = 32; o > 0; o >>= 1) sum += __shfl_xor(sum, o);
    float att = e / sum;
    if (lane < T) att_out[(size_t)(attRowOff + n) * T + lane] = att;
    float4 acc = {0.f, 0.f, 0.f, 0.f};
    for (int t = 0; t < T; ++t) {
        float a = __shfl(att, t);
        float4 o4 = *(const float4*)&outv[((size_t)n * T + t) * 256 + lane * 4];
        acc.x += a * o4.x; acc.y += a * o4.y; acc.z += a * o4.z; acc.w += a * o4.w;
    }
    *(float4*)&vec[(size_t)n * 256 + lane * 4] = acc;
}

// ---------------- head: logits, log-softmax, loss(+reg), predict, accuracy ----------------
__global__ __launch_bounds__(256) void head_kernel(
    const float* __restrict__ dvec, const float* __restrict__ wp, const float* __restrict__ bp,
    const int* __restrict__ y,
    const float* __restrict__ wa_l, const float* __restrict__ ba_l, const float* __restrict__ wa_h,
    const float* __restrict__ uw, const float* __restrict__ us,
    float* __restrict__ out)
{
    __shared__ float lg[64][10];
    __shared__ float red[256];
    int tid = threadIdx.x;
    for (int idx = tid; idx < 640; idx += 256) {
        int r = idx / 10, c = idx % 10;
        float a = bp[c];
        const float* dv = dvec + r * 256;
        for (int k = 0; k < 256; ++k) a += dv[k] * wp[k * 10 + c];
        lg[r][c] = a;
    }
    __syncthreads();
    float lossv = 0.f, corr = 0.f;
    if (tid < 64) {
        float m = lg[tid][0]; int arg = 0;
        for (int c = 1; c < 10; ++c) if (lg[tid][c] > m) { m = lg[tid][c]; arg = c; }
        float se = 0.f;
        for (int c = 0; c < 10; ++c) se += __expf(lg[tid][c] - m);
        float lse = m + __logf(se);
        int yy = y[tid];
        lossv = -(lg[tid][yy] - lse);
        corr = (yy == arg) ? 1.f : 0.f;
        out[1 + tid] = (float)arg;
    }
    float rs = 0.f;
    for (int i = tid; i < 32768; i += 256) {
        float v = wa_l[i]; rs += v * v;
        float w = wa_h[i]; rs += 2.f * w * w;
    }
    if (tid < 128) {
        float v1 = ba_l[tid], v2 = uw[tid], v3 = us[tid];
        rs += v1 * v1 + v2 * v2 + v3 * v3;
    }
    red[tid] = lossv; __syncthreads();
    for (int o = 128; o > 0; o >>= 1) { if (tid < o) red[tid] += red[tid + o]; __syncthreads(); }
    float totLoss = red[0]; __syncthreads();
    red[tid] = corr; __syncthreads();
    for (int o = 128; o > 0; o >>= 1) { if (tid < o) red[tid] += red[tid + o]; __syncthreads(); }
    float totCorr = red[0]; __syncthreads();
    red[tid] = rs; __syncthreads();
    for (int o = 128; o > 0; o >>= 1) { if (tid < o) red[tid] += red[tid + o]; __syncthreads(); }
    float totReg = red[0];
    if (tid == 0) {
        out[0] = totLoss / 64.f + 0.01f * totReg;
        out[65] = totCorr / 64.f;
    }
}

extern "C" void kernel_launch(void* const* d_in, const int* in_sizes, int n_in,
                              void* d_out, int out_size, void* d_ws, size_t ws_size,
                              hipStream_t stream)
{
    const float* X    = (const float*)d_in[0];
    const int*   y    = (const int*)d_in[1];
    const int*   slen = (const int*)d_in[2];
    const int*   dlen = (const int*)d_in[3];
    const float* wgf_l = (const float*)d_in[6];
    const float* bgf_l = (const float*)d_in[7];
    const float* wcf_l = (const float*)d_in[8];
    const float* bcf_l = (const float*)d_in[9];
    const float* wgb_l = (const float*)d_in[10];
    const float* bgb_l = (const float*)d_in[11];
    const float* wcb_l = (const float*)d_in[12];
    const float* bcb_l = (const float*)d_in[13];
    const float* wa_l  = (const float*)d_in[14];
    const float* ba_l  = (const float*)d_in[15];
    const float* wgf_h = (const float*)d_in[16];
    const float* bgf_h = (const float*)d_in[17];
    const float* wcf_h = (const float*)d_in[18];
    const float* bcf_h = (const float*)d_in[19];
    const float* wgb_h = (const float*)d_in[20];
    const float* bgb_h = (const float*)d_in[21];
    const float* wcb_h = (const float*)d_in[22];
    const float* bcb_h = (const float*)d_in[23];
    const float* wa_h  = (const float*)d_in[24];
    const float* ba_h  = (const float*)d_in[25];
    const float* uw    = (const float*)d_in[26];
    const float* us    = (const float*)d_in[27];
    const float* wp    = (const float*)d_in[28];
    const float* bp    = (const float*)d_in[29];
    float* out = (float*)d_out;

    // per-M1-row floats: G1 768 + low 256 + AXpack 224 = 1248; const ~6M floats
    int NCH = 1;
    while (NCH < 8) {
        size_t M1t = 128000ull / NCH;
        size_t needB = (M1t * 1248ull + 6000000ull) * 4ull;
        if (needB <= ws_size) break;
        NCH *= 2;
    }
    size_t nRows = 2560 / NCH;
    size_t M1 = nRows * 50;

    float* G1     = (float*)d_ws;            // M1*768; reused for ALpack+proj after bigru
    float* low    = G1 + M1 * 768;           // M1*256
    float* AXf    = low + M1 * 256;          // M1*224 (AXh M1*112, AXl M1*112)
    float* sent   = AXf + M1 * 224;          // 655360
    float* Gs     = sent + 655360;           // 1966080
    float* high   = Gs + 1966080;            // 655360
    float* projs  = high + 655360;           // 327680
    float* dvec   = projs + 327680;          // 16384
    float* pSf    = dvec + 16384;            // sent pack hi/lo: 2*327680
    float* pHf    = pSf + 655360;            // high pack hi/lo: 2*327680
    float* WpackL = pHf + 655360;            // 153600
    float* biasL  = WpackL + 153600;         // 768
    float* WLf    = biasL + 768;             // WLh 86016 + WLl 86016
    float* WpackH = WLf + 172032;            // 196608
    float* biasH  = WpackH + 196608;         // 768
    float* WHf    = biasH + 768;             // WHh 98304 + WHl 98304
    float* WaLf   = WHf + 196608;            // 16384 + 16384
    float* WaHf   = WaLf + 32768;            // 16384 + 16384

    uint4* AXh = (uint4*)AXf;           uint4* AXl = (uint4*)(AXf + M1 * 112);
    uint4* ALh = (uint4*)G1;            uint4* ALl = (uint4*)(G1 + M1 * 128);
    float* proj = G1 + M1 * 256;        // M1*128, inside dead G1 region
    uint4* pSh = (uint4*)pSf;           uint4* pSl = (uint4*)(pSf + 327680);
    uint4* pHh = (uint4*)pHf;           uint4* pHl = (uint4*)(pHf + 327680);
    uint4* WLh = (uint4*)WLf;           uint4* WLl = (uint4*)(WLf + 86016);
    uint4* WHh = (uint4*)WHf;           uint4* WHl = (uint4*)(WHf + 98304);
    uint4* WaLh = (uint4*)WaLf;         uint4* WaLl = (uint4*)(WaLf + 16384);
    uint4* WaHh = (uint4*)WaHf;         uint4* WaHl = (uint4*)(WaHf + 16384);

    // ---- one-time weight packing ----
    pack_weights<<<600, 256, 0, stream>>>(wgf_l, bgf_l, wcf_l, bcf_l, wgb_l, bgb_l, wcb_l, bcb_l,
                                          WpackL, biasL, 200);
    pack_weights<<<768, 256, 0, stream>>>(wgf_h, bgf_h, wcf_h, bcf_h, wgb_h, bgb_h, wcb_h, bcb_h,
                                          WpackH, biasH, 256);
    pack_w_frag<<<84, 256, 0, stream>>>(WpackL, WLh, WLl, 48, 7, 200, 768);
    pack_w_frag<<<96, 256, 0, stream>>>(WpackH, WHh, WHl, 48, 8, 256, 768);
    pack_w_frag<<<16, 256, 0, stream>>>(wa_l, WaLh, WaLl, 8, 8, 256, 128);
    pack_w_frag<<<16, 256, 0, stream>>>(wa_h, WaHh, WaHl, 8, 8, 256, 128);

    for (int c = 0; c < NCH; ++c) {
        const float* Xc = X + (size_t)c * nRows * 50 * 200;
        int Mr16 = (int)(M1 / 16);
        // pack X chunk -> frag order (K=200 pad 224, KC=7)
        pack_a_frag<<<(Mr16 * 7 * 64 + 255) / 256, 256, 0, stream>>>(Xc, AXh, AXl, Mr16, 7, 200);
        hipMemsetAsync(low, 0, M1 * 256 * sizeof(float), stream);
        // G1 = X @ Wpack + bias  (M1 x 768)
        mfma_gemm<<<dim3((int)(M1 / 128), 6), 256, 0, stream>>>(AXh, AXl, WLh, WLl, biasL, G1, 7, 768, 0);
        bigru_rnn<<<(int)(nRows / 8) * 2, 256, 0, stream>>>(G1,
            wgf_l + 200 * 256, wcf_l + 200 * 128, wgb_l + 200 * 256, wcb_l + 200 * 128,
            slen, low, (int)(c * nRows), 50);
        // pack low -> frag order (K=256, KC=8), into dead G1 region
        pack_a_frag<<<(Mr16 * 8 * 64 + 255) / 256, 256, 0, stream>>>(low, ALh, ALl, Mr16, 8, 256);
        // proj = tanh(low @ wa_l + ba_l)  (M1 x 128)
        mfma_gemm<<<dim3((int)(M1 / 128), 1), 256, 0, stream>>>(ALh, ALl, WaLh, WaLl, ba_l, proj, 8, 128, 1);
        attn_reduce<<<(int)nRows, 64, 0, stream>>>(proj, low, uw, out + 66, sent + (size_t)c * nRows * 256, 50, (int)(c * nRows));
    }
    // ---- sentence level ----
    pack_a_frag<<<(160 * 8 * 64 + 255) / 256, 256, 0, stream>>>(sent, pSh, pSl, 160, 8, 256);
    hipMemsetAsync(high, 0, 2560ull * 256 * sizeof(float), stream);
    mfma_gemm<<<dim3(20, 6), 256, 0, stream>>>(pSh, pSl, WHh, WHl, biasH, Gs, 8, 768, 0);
    bigru_rnn<<<16, 256, 0, stream>>>(Gs,
        wgf_h + 256 * 256, wcf_h + 256 * 128, wgb_h + 256 * 256, wcb_h + 256 * 128,
        dlen, high, 0, 40);
    pack_a_frag<<<(160 * 8 * 64 + 255) / 256, 256, 0, stream>>>(high, pHh, pHl, 160, 8, 256);
    mfma_gemm<<<dim3(20, 1), 256, 0, stream>>>(pHh, pHl, WaHh, WaHl, ba_h, projs, 8, 128, 1);
    attn_reduce<<<64, 64, 0, stream>>>(projs, high, us, out + 128066, dvec, 40, 0);
    head_kernel<<<1, 256, 0, stream>>>(dvec, wp, bp, y, wa_l, ba_l, wa_h, uw, us, out);
}

// Round 4
// 1341.043 us; speedup vs baseline: 6.9410x; 1.6535x over previous
//
#include <hip/hip_runtime.h>
#include <hip/hip_bf16.h>

// HAN_81801947119983 — round 4: MFMA recurrence (split-bf16, prepacked h-weights).
// B=64, D=40, S=50, E=200, H=128, C=10. N1=2560 word rows (T=50), 64 doc rows (T=40).
// G cols: [0:256) fw gates, [256:384) fw cand, [384:640) bw gates, [640:768) bw cand.
// MFMA 16x16x32 bf16 layouts (HW-verified per guide):
//   A frag: lane holds A[m=lane&15][k=quad*8+j], j=0..7. B frag: B[k=quad*8+j][n=lane&15].
//   C/D: col=lane&15, row=quad*4+reg.
// Pack (uint4 idx): ((tile16*KC + kc)*4 + quad)*16 + (lane&15) — wave frag load = 1KB contiguous.

typedef __attribute__((ext_vector_type(8))) short short8;
typedef __attribute__((ext_vector_type(4))) float f32x4;

__device__ __forceinline__ float fsigmoid(float x) { return 1.f / (1.f + __expf(-x)); }
__device__ __forceinline__ float ftanh(float x)    { float e = __expf(2.f * x); return 1.f - 2.f / (e + 1.f); }

__device__ __forceinline__ unsigned short f2bf(float x) {
    unsigned int u = __builtin_bit_cast(unsigned int, x);
    u += 0x7fffu + ((u >> 16) & 1u);
    return (unsigned short)(u >> 16);
}
__device__ __forceinline__ float bf2f(unsigned short h) {
    unsigned int u = ((unsigned int)h) << 16;
    return __builtin_bit_cast(float, u);
}
__device__ __forceinline__ uint4 pack8(const unsigned short* v) {
    uint4 r;
    r.x = (unsigned int)v[0] | ((unsigned int)v[1] << 16);
    r.y = (unsigned int)v[2] | ((unsigned int)v[3] << 16);
    r.z = (unsigned int)v[4] | ((unsigned int)v[5] << 16);
    r.w = (unsigned int)v[6] | ((unsigned int)v[7] << 16);
    return r;
}
__device__ __forceinline__ void cvt8(const float* v, short8& hi, short8& lo) {
    unsigned short h[8], l[8];
#pragma unroll
    for (int j = 0; j < 8; ++j) {
        unsigned short hh = f2bf(v[j]);
        h[j] = hh;
        l[j] = f2bf(v[j] - bf2f(hh));
    }
    uint4 uh = pack8(h), ul = pack8(l);
    hi = __builtin_bit_cast(short8, uh);
    lo = __builtin_bit_cast(short8, ul);
}

// ---------------- weight concat: W[E,768] = [wg_f | wc_f | wg_b | wc_b], bias[768] ----------------
__global__ __launch_bounds__(256) void pack_weights(
    const float* __restrict__ wg_f, const float* __restrict__ bg_f,
    const float* __restrict__ wc_f, const float* __restrict__ bc_f,
    const float* __restrict__ wg_b, const float* __restrict__ bg_b,
    const float* __restrict__ wc_b, const float* __restrict__ bc_b,
    float* __restrict__ W, float* __restrict__ bias, int E)
{
    int idx = blockIdx.x * 256 + threadIdx.x;
    if (idx < 768) {
        int c = idx; float v;
        if (c < 256) v = bg_f[c];
        else if (c < 384) v = bc_f[c - 256];
        else if (c < 640) v = bg_b[c - 384];
        else v = bc_b[c - 640];
        bias[c] = v;
    }
    if (idx >= E * 768) return;
    int k = idx / 768, c = idx - k * 768;
    float v;
    if (c < 256) v = wg_f[k * 256 + c];
    else if (c < 384) v = wc_f[k * 128 + (c - 256)];
    else if (c < 640) v = wg_b[k * 256 + (c - 384)];
    else v = wc_b[k * 128 + (c - 640)];
    W[idx] = v;
}

// ---------------- pack A (row-major [Mr x Ks] fp32) into frag-order hi/lo bf16 ----------------
__global__ __launch_bounds__(256) void pack_a_frag(
    const float* __restrict__ src, uint4* __restrict__ dstH, uint4* __restrict__ dstL,
    int Mr16, int KC, int Ks)
{
    int idx = blockIdx.x * 256 + threadIdx.x;
    if (idx >= Mr16 * KC * 64) return;
    int lane = idx & 63;
    int g = idx >> 6;
    int mb = g / KC, kc = g - mb * KC;
    int m = lane & 15, quad = lane >> 4;
    int row = mb * 16 + m;
    int k0 = kc * 32 + quad * 8;
    const float* s = src + (size_t)row * Ks;
    unsigned short hi[8], lo[8];
#pragma unroll
    for (int j = 0; j < 8; ++j) {
        float x = (k0 + j < Ks) ? s[k0 + j] : 0.f;
        unsigned short h = f2bf(x);
        hi[j] = h;
        lo[j] = f2bf(x - bf2f(h));
    }
    dstH[idx] = pack8(hi);
    dstL[idx] = pack8(lo);
}

// ---------------- pack W (row-major [Ks x N] fp32) into frag-order hi/lo bf16 ----------------
__global__ __launch_bounds__(256) void pack_w_frag(
    const float* __restrict__ src, uint4* __restrict__ dstH, uint4* __restrict__ dstL,
    int N16, int KC, int Ks, int N)
{
    int idx = blockIdx.x * 256 + threadIdx.x;
    if (idx >= N16 * KC * 64) return;
    int lane = idx & 63;
    int g = idx >> 6;
    int nb = g / KC, kc = g - nb * KC;
    int m = lane & 15, quad = lane >> 4;
    int n = nb * 16 + m;
    int k0 = kc * 32 + quad * 8;
    unsigned short hi[8], lo[8];
#pragma unroll
    for (int j = 0; j < 8; ++j) {
        float x = (k0 + j < Ks) ? src[(size_t)(k0 + j) * N + n] : 0.f;
        unsigned short h = f2bf(x);
        hi[j] = h;
        lo[j] = f2bf(x - bf2f(h));
    }
    dstH[idx] = pack8(hi);
    dstL[idx] = pack8(lo);
}

// ---------------- MFMA GEMM: C = act(A @ W + bias), split-bf16 3-product ----------------
__global__ __launch_bounds__(256) void mfma_gemm(
    const uint4* __restrict__ Ah, const uint4* __restrict__ Al,
    const uint4* __restrict__ Bh, const uint4* __restrict__ Bl,
    const float* __restrict__ bias, float* __restrict__ C,
    int KC, int ldc, int act)
{
    int tid = threadIdx.x;
    int lane = tid & 63;
    int w = tid >> 6;
    int wm = w >> 1, wn = w & 1;
    int quad = lane >> 4, m = lane & 15;
    int bm = blockIdx.x, bn = blockIdx.y;
    f32x4 acc[4][4];
#pragma unroll
    for (int i = 0; i < 4; ++i)
#pragma unroll
        for (int j = 0; j < 4; ++j) acc[i][j] = (f32x4){0.f, 0.f, 0.f, 0.f};

    size_t aBase[4], bBase[4];
#pragma unroll
    for (int i = 0; i < 4; ++i) {
        aBase[i] = ((size_t)(bm * 8 + wm * 4 + i) * KC) * 64 + quad * 16 + m;
        bBase[i] = ((size_t)(bn * 8 + wn * 4 + i) * KC) * 64 + quad * 16 + m;
    }
    for (int kc = 0; kc < KC; ++kc) {
        short8 ah[4], al[4], bh[4], bl[4];
#pragma unroll
        for (int i = 0; i < 4; ++i) {
            ah[i] = __builtin_bit_cast(short8, Ah[aBase[i]]);
            al[i] = __builtin_bit_cast(short8, Al[aBase[i]]);
            bh[i] = __builtin_bit_cast(short8, Bh[bBase[i]]);
            bl[i] = __builtin_bit_cast(short8, Bl[bBase[i]]);
            aBase[i] += 64; bBase[i] += 64;
        }
#pragma unroll
        for (int i = 0; i < 4; ++i)
#pragma unroll
            for (int j = 0; j < 4; ++j) {
                acc[i][j] = __builtin_amdgcn_mfma_f32_16x16x32_bf16(ah[i], bh[j], acc[i][j], 0, 0, 0);
                acc[i][j] = __builtin_amdgcn_mfma_f32_16x16x32_bf16(ah[i], bl[j], acc[i][j], 0, 0, 0);
                acc[i][j] = __builtin_amdgcn_mfma_f32_16x16x32_bf16(al[i], bh[j], acc[i][j], 0, 0, 0);
            }
    }
#pragma unroll
    for (int i = 0; i < 4; ++i) {
        int row0 = bm * 128 + wm * 64 + i * 16 + quad * 4;
#pragma unroll
        for (int j = 0; j < 4; ++j) {
            int col = bn * 128 + wn * 64 + j * 16 + m;
            float b = bias[col];
#pragma unroll
            for (int r = 0; r < 4; ++r) {
                float v = acc[i][j][r] + b;
                if (act) v = ftanh(v);
                C[(size_t)(row0 + r) * ldc + col] = v;
            }
        }
    }
}

// ---------------- MFMA BiGRU recurrence: 16 rows x 1 dir per block, 4 waves ----------------
// State h fp32 in LDS [16][132]; recurrent weights prepacked B-frag hi/lo.
// Per step: prefetch G, build h A-frags (split bf16), gates MFMA (16 n-tiles / 4 waves),
// elementwise -> rh,z in LDS, barrier, cand A-frags, cand MFMA (8 n-tiles / 4 waves),
// h update + out write (zeros at invalid steps -> no memset needed), barrier.
__global__ __launch_bounds__(256) void bigru_mfma(
    const float* __restrict__ G,      // [nRows*T, 768] chunk-local
    const uint4* __restrict__ WgH, const uint4* __restrict__ WgL,  // [2 dirs][16 nt][4 kc][64]
    const uint4* __restrict__ WcH, const uint4* __restrict__ WcL,  // [2 dirs][8 nt][4 kc][64]
    const int* __restrict__ lens,     // global
    float* __restrict__ outbuf,       // [nRows*T, 256] chunk-local
    int rowOff, int T)
{
    __shared__ float hs[16][132];
    __shared__ float rs_[16][132];
    __shared__ float zs[16][132];
    __shared__ int Ls[16];

    int tid = threadIdx.x;
    int dir = blockIdx.x & 1;
    int rg0 = (blockIdx.x >> 1) * 16;
    int lane = tid & 63, w = tid >> 6;
    int quad = lane >> 4, mc = lane & 15;
    for (int i = tid; i < 16 * 132; i += 256) (&hs[0][0])[i] = 0.f;
    if (tid < 16) Ls[tid] = lens[rowOff + rg0 + tid];
    __syncthreads();
    const int goff = dir * 384;

    for (int t = 0; t < T; ++t) {
        // per-row valid/time for this lane's elementwise rows (m = quad*4 + r)
        int Lr[4], tir[4];
#pragma unroll
        for (int r = 0; r < 4; ++r) {
            int L = Ls[quad * 4 + r];
            Lr[r] = L;
            tir[r] = dir ? ((t < L) ? (L - 1 - t) : t) : t;
        }
        // prefetch G (in flight under MFMAs)
        float gG[4][4], gC[2][4];
#pragma unroll
        for (int r = 0; r < 4; ++r) {
            const float* gbase = &G[((size_t)(rg0 + quad * 4 + r) * T + tir[r]) * 768 + goff];
#pragma unroll
            for (int i = 0; i < 4; ++i) gG[i][r] = gbase[(w * 4 + i) * 16 + mc];
#pragma unroll
            for (int i = 0; i < 2; ++i) gC[i][r] = gbase[256 + (w * 2 + i) * 16 + mc];
        }
        // build h A-frags
        short8 ahh[4], ahl[4];
#pragma unroll
        for (int kc = 0; kc < 4; ++kc) {
            float v[8];
            const float* hp = &hs[mc][kc * 32 + quad * 8];
#pragma unroll
            for (int j = 0; j < 8; ++j) v[j] = hp[j];
            cvt8(v, ahh[kc], ahl[kc]);
        }
        // gates MFMA: wave handles n-tiles w*4..w*4+3 of 16
        f32x4 ga[4];
#pragma unroll
        for (int i = 0; i < 4; ++i) ga[i] = (f32x4){0.f, 0.f, 0.f, 0.f};
#pragma unroll
        for (int kc = 0; kc < 4; ++kc) {
#pragma unroll
            for (int i = 0; i < 4; ++i) {
                size_t idx = (((size_t)(dir * 16 + w * 4 + i) * 4 + kc) << 6) + lane;
                short8 bh = __builtin_bit_cast(short8, WgH[idx]);
                short8 bl = __builtin_bit_cast(short8, WgL[idx]);
                ga[i] = __builtin_amdgcn_mfma_f32_16x16x32_bf16(ahh[kc], bh, ga[i], 0, 0, 0);
                ga[i] = __builtin_amdgcn_mfma_f32_16x16x32_bf16(ahh[kc], bl, ga[i], 0, 0, 0);
                ga[i] = __builtin_amdgcn_mfma_f32_16x16x32_bf16(ahl[kc], bh, ga[i], 0, 0, 0);
            }
        }
        // gates elementwise: rh = sig(r)*h, z = sig(z)
#pragma unroll
        for (int i = 0; i < 4; ++i) {
            int n = (w * 4 + i) * 16 + mc;
#pragma unroll
            for (int r = 0; r < 4; ++r) {
                int m = quad * 4 + r;
                float s = fsigmoid(ga[i][r] + gG[i][r]);
                if (n < 128) rs_[m][n] = s * hs[m][n];
                else zs[m][n - 128] = s;
            }
        }
        __syncthreads();
        // cand A-frags from rh
        short8 arh[4], arl[4];
#pragma unroll
        for (int kc = 0; kc < 4; ++kc) {
            float v[8];
            const float* rp = &rs_[mc][kc * 32 + quad * 8];
#pragma unroll
            for (int j = 0; j < 8; ++j) v[j] = rp[j];
            cvt8(v, arh[kc], arl[kc]);
        }
        // cand MFMA: wave handles n-tiles w*2..w*2+1 of 8
        f32x4 ca[2];
#pragma unroll
        for (int i = 0; i < 2; ++i) ca[i] = (f32x4){0.f, 0.f, 0.f, 0.f};
#pragma unroll
        for (int kc = 0; kc < 4; ++kc) {
#pragma unroll
            for (int i = 0; i < 2; ++i) {
                size_t idx = (((size_t)(dir * 8 + w * 2 + i) * 4 + kc) << 6) + lane;
                short8 bh = __builtin_bit_cast(short8, WcH[idx]);
                short8 bl = __builtin_bit_cast(short8, WcL[idx]);
                ca[i] = __builtin_amdgcn_mfma_f32_16x16x32_bf16(arh[kc], bh, ca[i], 0, 0, 0);
                ca[i] = __builtin_amdgcn_mfma_f32_16x16x32_bf16(arh[kc], bl, ca[i], 0, 0, 0);
                ca[i] = __builtin_amdgcn_mfma_f32_16x16x32_bf16(arl[kc], bh, ca[i], 0, 0, 0);
            }
        }
        // cand elementwise + h update + out write (zeros when invalid)
#pragma unroll
        for (int i = 0; i < 2; ++i) {
            int n = (w * 2 + i) * 16 + mc;
#pragma unroll
            for (int r = 0; r < 4; ++r) {
                int m = quad * 4 + r;
                bool valid = (t < Lr[r]);
                float cd = ftanh(ca[i][r] + gC[i][r]);
                float z = zs[m][n];
                float h = hs[m][n];
                float hn = z * h + (1.f - z) * cd;
                float ov = valid ? hn : 0.f;
                if (valid) hs[m][n] = hn;
                outbuf[((size_t)(rg0 + m) * T + tir[r]) * 256 + dir * 128 + n] = ov;
            }
        }
        __syncthreads();
    }
}

// ---------------- attention score/softmax/weighted-sum: 1 wave per row ----------------
__global__ __launch_bounds__(64) void attn_reduce(
    const float* __restrict__ proj, const float* __restrict__ outv,
    const float* __restrict__ u,
    float* __restrict__ att_out, float* __restrict__ vec,
    int T, int attRowOff)
{
    int n = blockIdx.x, lane = threadIdx.x;
    float s = 0.f;
    if (lane < T) {
        const float4* p = (const float4*)(proj + ((size_t)n * T + lane) * 128);
        const float4* uu = (const float4*)u;
        for (int k = 0; k < 32; ++k) {
            float4 a = p[k], b = uu[k];
            s += a.x * b.x + a.y * b.y + a.z * b.z + a.w * b.w;
        }
    }
    float m = (lane < T) ? s : -3.402823466e38f;
    for (int o = 32; o > 0; o >>= 1) m = fmaxf(m, __shfl_xor(m, o));
    float e = (lane < T) ? __expf(s - m) : 0.f;
    float sum = e;
    for (int o = 32; o > 0; o >>= 1) sum += __shfl_xor(sum, o);
    float att = e / sum;
    if (lane < T) att_out[(size_t)(attRowOff + n) * T + lane] = att;
    float4 acc = {0.f, 0.f, 0.f, 0.f};
    for (int t = 0; t < T; ++t) {
        float a = __shfl(att, t);
        float4 o4 = *(const float4*)&outv[((size_t)n * T + t) * 256 + lane * 4];
        acc.x += a * o4.x; acc.y += a * o4.y; acc.z += a * o4.z; acc.w += a * o4.w;
    }
    *(float4*)&vec[(size_t)n * 256 + lane * 4] = acc;
}

// ---------------- head: logits, log-softmax, loss(+reg), predict, accuracy ----------------
__global__ __launch_bounds__(256) void head_kernel(
    const float* __restrict__ dvec, const float* __restrict__ wp, const float* __restrict__ bp,
    const int* __restrict__ y,
    const float* __restrict__ wa_l, const float* __restrict__ ba_l, const float* __restrict__ wa_h,
    const float* __restrict__ uw, const float* __restrict__ us,
    float* __restrict__ out)
{
    __shared__ float lg[64][10];
    __shared__ float red[256];
    int tid = threadIdx.x;
    for (int idx = tid; idx < 640; idx += 256) {
        int r = idx / 10, c = idx % 10;
        float a = bp[c];
        const float* dv = dvec + r * 256;
        for (int k = 0; k < 256; ++k) a += dv[k] * wp[k * 10 + c];
        lg[r][c] = a;
    }
    __syncthreads();
    float lossv = 0.f, corr = 0.f;
    if (tid < 64) {
        float m = lg[tid][0]; int arg = 0;
        for (int c = 1; c < 10; ++c) if (lg[tid][c] > m) { m = lg[tid][c]; arg = c; }
        float se = 0.f;
        for (int c = 0; c < 10; ++c) se += __expf(lg[tid][c] - m);
        float lse = m + __logf(se);
        int yy = y[tid];
        lossv = -(lg[tid][yy] - lse);
        corr = (yy == arg) ? 1.f : 0.f;
        out[1 + tid] = (float)arg;
    }
    float rs = 0.f;
    for (int i = tid; i < 32768; i += 256) {
        float v = wa_l[i]; rs += v * v;
        float w = wa_h[i]; rs += 2.f * w * w;
    }
    if (tid < 128) {
        float v1 = ba_l[tid], v2 = uw[tid], v3 = us[tid];
        rs += v1 * v1 + v2 * v2 + v3 * v3;
    }
    red[tid] = lossv; __syncthreads();
    for (int o = 128; o > 0; o >>= 1) { if (tid < o) red[tid] += red[tid + o]; __syncthreads(); }
    float totLoss = red[0]; __syncthreads();
    red[tid] = corr; __syncthreads();
    for (int o = 128; o > 0; o >>= 1) { if (tid < o) red[tid] += red[tid + o]; __syncthreads(); }
    float totCorr = red[0]; __syncthreads();
    red[tid] = rs; __syncthreads();
    for (int o = 128; o > 0; o >>= 1) { if (tid < o) red[tid] += red[tid + o]; __syncthreads(); }
    float totReg = red[0];
    if (tid == 0) {
        out[0] = totLoss / 64.f + 0.01f * totReg;
        out[65] = totCorr / 64.f;
    }
}

extern "C" void kernel_launch(void* const* d_in, const int* in_sizes, int n_in,
                              void* d_out, int out_size, void* d_ws, size_t ws_size,
                              hipStream_t stream)
{
    const float* X    = (const float*)d_in[0];
    const int*   y    = (const int*)d_in[1];
    const int*   slen = (const int*)d_in[2];
    const int*   dlen = (const int*)d_in[3];
    const float* wgf_l = (const float*)d_in[6];
    const float* bgf_l = (const float*)d_in[7];
    const float* wcf_l = (const float*)d_in[8];
    const float* bcf_l = (const float*)d_in[9];
    const float* wgb_l = (const float*)d_in[10];
    const float* bgb_l = (const float*)d_in[11];
    const float* wcb_l = (const float*)d_in[12];
    const float* bcb_l = (const float*)d_in[13];
    const float* wa_l  = (const float*)d_in[14];
    const float* ba_l  = (const float*)d_in[15];
    const float* wgf_h = (const float*)d_in[16];
    const float* bgf_h = (const float*)d_in[17];
    const float* wcf_h = (const float*)d_in[18];
    const float* bcf_h = (const float*)d_in[19];
    const float* wgb_h = (const float*)d_in[20];
    const float* bgb_h = (const float*)d_in[21];
    const float* wcb_h = (const float*)d_in[22];
    const float* bcb_h = (const float*)d_in[23];
    const float* wa_h  = (const float*)d_in[24];
    const float* ba_h  = (const float*)d_in[25];
    const float* uw    = (const float*)d_in[26];
    const float* us    = (const float*)d_in[27];
    const float* wp    = (const float*)d_in[28];
    const float* bp    = (const float*)d_in[29];
    float* out = (float*)d_out;

    // per-M1-row floats: G1 768 + low 256 + AXpack 224 = 1248; const ~6M floats
    int NCH = 1;
    while (NCH < 8) {
        size_t M1t = 128000ull / NCH;
        size_t needB = (M1t * 1248ull + 6000000ull) * 4ull;
        if (needB <= ws_size) break;
        NCH *= 2;
    }
    size_t nRows = 2560 / NCH;
    size_t M1 = nRows * 50;

    float* G1     = (float*)d_ws;            // M1*768; reused for ALpack+proj after bigru
    float* low    = G1 + M1 * 768;           // M1*256
    float* AXf    = low + M1 * 256;          // M1*224
    float* sent   = AXf + M1 * 224;          // 655360
    float* Gs     = sent + 655360;           // 1966080
    float* high   = Gs + 1966080;            // 655360
    float* projs  = high + 655360;           // 327680
    float* dvec   = projs + 327680;          // 16384
    float* pSf    = dvec + 16384;            // 655360
    float* pHf    = pSf + 655360;            // 655360
    float* WpackL = pHf + 655360;            // 153600
    float* biasL  = WpackL + 153600;         // 768
    float* WLf    = biasL + 768;             // 172032
    float* WpackH = WLf + 172032;            // 196608
    float* biasH  = WpackH + 196608;         // 768
    float* WHf    = biasH + 768;             // 196608
    float* WaLf   = WHf + 196608;            // 32768
    float* WaHf   = WaLf + 32768;            // 32768
    float* RgLf   = WaHf + 32768;            // 65536 (hi 32768 + lo 32768)
    float* RcLf   = RgLf + 65536;            // 32768 (hi 16384 + lo 16384)
    float* RgHf   = RcLf + 32768;            // 65536
    float* RcHf   = RgHf + 65536;            // 32768

    uint4* AXh = (uint4*)AXf;           uint4* AXl = (uint4*)(AXf + M1 * 112);
    uint4* ALh = (uint4*)G1;            uint4* ALl = (uint4*)(G1 + M1 * 128);
    float* proj = G1 + M1 * 256;
    uint4* pSh = (uint4*)pSf;           uint4* pSl = (uint4*)(pSf + 327680);
    uint4* pHh = (uint4*)pHf;           uint4* pHl = (uint4*)(pHf + 327680);
    uint4* WLh = (uint4*)WLf;           uint4* WLl = (uint4*)(WLf + 86016);
    uint4* WHh = (uint4*)WHf;           uint4* WHl = (uint4*)(WHf + 98304);
    uint4* WaLh = (uint4*)WaLf;         uint4* WaLl = (uint4*)(WaLf + 16384);
    uint4* WaHh = (uint4*)WaHf;         uint4* WaHl = (uint4*)(WaHf + 16384);
    uint4* RgLH = (uint4*)RgLf;         uint4* RgLL = (uint4*)(RgLf + 32768);
    uint4* RcLH = (uint4*)RcLf;         uint4* RcLL = (uint4*)(RcLf + 16384);
    uint4* RgHH = (uint4*)RgHf;         uint4* RgHL = (uint4*)(RgHf + 32768);
    uint4* RcHH = (uint4*)RcHf;         uint4* RcHL = (uint4*)(RcHf + 16384);

    // ---- one-time weight packing ----
    pack_weights<<<600, 256, 0, stream>>>(wgf_l, bgf_l, wcf_l, bcf_l, wgb_l, bgb_l, wcb_l, bcb_l,
                                          WpackL, biasL, 200);
    pack_weights<<<768, 256, 0, stream>>>(wgf_h, bgf_h, wcf_h, bcf_h, wgb_h, bgb_h, wcb_h, bcb_h,
                                          WpackH, biasH, 256);
    pack_w_frag<<<84, 256, 0, stream>>>(WpackL, WLh, WLl, 48, 7, 200, 768);
    pack_w_frag<<<96, 256, 0, stream>>>(WpackH, WHh, WHl, 48, 8, 256, 768);
    pack_w_frag<<<16, 256, 0, stream>>>(wa_l, WaLh, WaLl, 8, 8, 256, 128);
    pack_w_frag<<<16, 256, 0, stream>>>(wa_h, WaHh, WaHl, 8, 8, 256, 128);
    // recurrent h-part weights, B-frag order, per dir (gates [16nt,4kc], cand [8nt,4kc])
    pack_w_frag<<<16, 256, 0, stream>>>(wgf_l + 200 * 256, RgLH,        RgLL,        16, 4, 128, 256);
    pack_w_frag<<<16, 256, 0, stream>>>(wgb_l + 200 * 256, RgLH + 4096, RgLL + 4096, 16, 4, 128, 256);
    pack_w_frag<<< 8, 256, 0, stream>>>(wcf_l + 200 * 128, RcLH,        RcLL,         8, 4, 128, 128);
    pack_w_frag<<< 8, 256, 0, stream>>>(wcb_l + 200 * 128, RcLH + 2048, RcLL + 2048,  8, 4, 128, 128);
    pack_w_frag<<<16, 256, 0, stream>>>(wgf_h + 256 * 256, RgHH,        RgHL,        16, 4, 128, 256);
    pack_w_frag<<<16, 256, 0, stream>>>(wgb_h + 256 * 256, RgHH + 4096, RgHL + 4096, 16, 4, 128, 256);
    pack_w_frag<<< 8, 256, 0, stream>>>(wcf_h + 256 * 128, RcHH,        RcHL,         8, 4, 128, 128);
    pack_w_frag<<< 8, 256, 0, stream>>>(wcb_h + 256 * 128, RcHH + 2048, RcHL + 2048,  8, 4, 128, 128);

    for (int c = 0; c < NCH; ++c) {
        const float* Xc = X + (size_t)c * nRows * 50 * 200;
        int Mr16 = (int)(M1 / 16);
        pack_a_frag<<<(Mr16 * 7 * 64 + 255) / 256, 256, 0, stream>>>(Xc, AXh, AXl, Mr16, 7, 200);
        mfma_gemm<<<dim3((int)(M1 / 128), 6), 256, 0, stream>>>(AXh, AXl, WLh, WLl, biasL, G1, 7, 768, 0);
        bigru_mfma<<<(int)(nRows / 16) * 2, 256, 0, stream>>>(G1, RgLH, RgLL, RcLH, RcLL,
                                                              slen, low, (int)(c * nRows), 50);
        pack_a_frag<<<(Mr16 * 8 * 64 + 255) / 256, 256, 0, stream>>>(low, ALh, ALl, Mr16, 8, 256);
        mfma_gemm<<<dim3((int)(M1 / 128), 1), 256, 0, stream>>>(ALh, ALl, WaLh, WaLl, ba_l, proj, 8, 128, 1);
        attn_reduce<<<(int)nRows, 64, 0, stream>>>(proj, low, uw, out + 66, sent + (size_t)c * nRows * 256, 50, (int)(c * nRows));
    }
    // ---- sentence level ----
    pack_a_frag<<<(160 * 8 * 64 + 255) / 256, 256, 0, stream>>>(sent, pSh, pSl, 160, 8, 256);
    mfma_gemm<<<dim3(20, 6), 256, 0, stream>>>(pSh, pSl, WHh, WHl, biasH, Gs, 8, 768, 0);
    bigru_mfma<<<8, 256, 0, stream>>>(Gs, RgHH, RgHL, RcHH, RcHL, dlen, high, 0, 40);
    pack_a_frag<<<(160 * 8 * 64 + 255) / 256, 256, 0, stream>>>(high, pHh, pHl, 160, 8, 256);
    mfma_gemm<<<dim3(20, 1), 256, 0, stream>>>(pHh, pHl, WaHh, WaHl, ba_h, projs, 8, 128, 1);
    attn_reduce<<<64, 64, 0, stream>>>(projs, high, us, out + 128066, dvec, 40, 0);
    head_kernel<<<1, 256, 0, stream>>>(dvec, wp, bp, y, wa_l, ba_l, wa_h, uw, us, out);
}

// Round 5
// 1237.056 us; speedup vs baseline: 7.5245x; 1.0841x over previous
//
#include <hip/hip_runtime.h>
#include <hip/hip_bf16.h>

// HAN_81801947119983 — round 5: bf16-mirrored bigru state (no per-wave frag rebuild),
// fused attention (pack+proj+softmax+wsum in one kernel), merged pack launches.
// B=64, D=40, S=50, E=200, H=128, C=10. N1=2560 word rows (T=50), 64 doc rows (T=40).
// G cols: [0:256) fw gates, [256:384) fw cand, [384:640) bw gates, [640:768) bw cand.
// MFMA 16x16x32 bf16: A frag lane holds A[m=lane&15][k=quad*8+j]; B frag B[k][n=lane&15];
// C/D col=lane&15, row=quad*4+reg.  Pack uint4 idx: ((tile*KC+kc)*4+quad)*16+(lane&15).

typedef __attribute__((ext_vector_type(8))) short short8;
typedef __attribute__((ext_vector_type(4))) float f32x4;

__device__ __forceinline__ float fsigmoid(float x) { return 1.f / (1.f + __expf(-x)); }
__device__ __forceinline__ float ftanh(float x)    { float e = __expf(2.f * x); return 1.f - 2.f / (e + 1.f); }

__device__ __forceinline__ unsigned short f2bf(float x) {
    unsigned int u = __builtin_bit_cast(unsigned int, x);
    u += 0x7fffu + ((u >> 16) & 1u);
    return (unsigned short)(u >> 16);
}
__device__ __forceinline__ float bf2f(unsigned short h) {
    unsigned int u = ((unsigned int)h) << 16;
    return __builtin_bit_cast(float, u);
}
__device__ __forceinline__ uint4 pack8(const unsigned short* v) {
    uint4 r;
    r.x = (unsigned int)v[0] | ((unsigned int)v[1] << 16);
    r.y = (unsigned int)v[2] | ((unsigned int)v[3] << 16);
    r.z = (unsigned int)v[4] | ((unsigned int)v[5] << 16);
    r.w = (unsigned int)v[6] | ((unsigned int)v[7] << 16);
    return r;
}
__device__ __forceinline__ void cvt8(const float* v, short8& hi, short8& lo) {
    unsigned short h[8], l[8];
#pragma unroll
    for (int j = 0; j < 8; ++j) {
        unsigned short hh = f2bf(v[j]);
        h[j] = hh;
        l[j] = f2bf(v[j] - bf2f(hh));
    }
    uint4 uh = pack8(h), ul = pack8(l);
    hi = __builtin_bit_cast(short8, uh);
    lo = __builtin_bit_cast(short8, ul);
}

// ---------------- weight concat: W[E,768] = [wg_f | wc_f | wg_b | wc_b], bias[768] ----------------
__global__ __launch_bounds__(256) void pack_weights(
    const float* __restrict__ wg_f, const float* __restrict__ bg_f,
    const float* __restrict__ wc_f, const float* __restrict__ bc_f,
    const float* __restrict__ wg_b, const float* __restrict__ bg_b,
    const float* __restrict__ wc_b, const float* __restrict__ bc_b,
    float* __restrict__ W, float* __restrict__ bias, int E)
{
    int idx = blockIdx.x * 256 + threadIdx.x;
    if (idx < 768) {
        int c = idx; float v;
        if (c < 256) v = bg_f[c];
        else if (c < 384) v = bc_f[c - 256];
        else if (c < 640) v = bg_b[c - 384];
        else v = bc_b[c - 640];
        bias[c] = v;
    }
    if (idx >= E * 768) return;
    int k = idx / 768, c = idx - k * 768;
    float v;
    if (c < 256) v = wg_f[k * 256 + c];
    else if (c < 384) v = wc_f[k * 128 + (c - 256)];
    else if (c < 640) v = wg_b[k * 256 + (c - 384)];
    else v = wc_b[k * 128 + (c - 640)];
    W[idx] = v;
}

// ---------------- pack A (row-major [Mr x Ks] fp32) into frag-order hi/lo bf16 ----------------
__global__ __launch_bounds__(256) void pack_a_frag(
    const float* __restrict__ src, uint4* __restrict__ dstH, uint4* __restrict__ dstL,
    int Mr16, int KC, int Ks)
{
    int idx = blockIdx.x * 256 + threadIdx.x;
    if (idx >= Mr16 * KC * 64) return;
    int lane = idx & 63;
    int g = idx >> 6;
    int mb = g / KC, kc = g - mb * KC;
    int m = lane & 15, quad = lane >> 4;
    int row = mb * 16 + m;
    int k0 = kc * 32 + quad * 8;
    const float* s = src + (size_t)row * Ks;
    unsigned short hi[8], lo[8];
#pragma unroll
    for (int j = 0; j < 8; ++j) {
        float x = (k0 + j < Ks) ? s[k0 + j] : 0.f;
        unsigned short h = f2bf(x);
        hi[j] = h;
        lo[j] = f2bf(x - bf2f(h));
    }
    dstH[idx] = pack8(hi);
    dstL[idx] = pack8(lo);
}

// ---------------- pack W (row-major [Ks x N] fp32) into frag-order hi/lo bf16 ----------------
__global__ __launch_bounds__(256) void pack_w_frag(
    const float* __restrict__ src, uint4* __restrict__ dstH, uint4* __restrict__ dstL,
    int N16, int KC, int Ks, int N)
{
    int idx = blockIdx.x * 256 + threadIdx.x;
    if (idx >= N16 * KC * 64) return;
    int lane = idx & 63;
    int g = idx >> 6;
    int nb = g / KC, kc = g - nb * KC;
    int m = lane & 15, quad = lane >> 4;
    int n = nb * 16 + m;
    int k0 = kc * 32 + quad * 8;
    unsigned short hi[8], lo[8];
#pragma unroll
    for (int j = 0; j < 8; ++j) {
        float x = (k0 + j < Ks) ? src[(size_t)(k0 + j) * N + n] : 0.f;
        unsigned short h = f2bf(x);
        hi[j] = h;
        lo[j] = f2bf(x - bf2f(h));
    }
    dstH[idx] = pack8(hi);
    dstL[idx] = pack8(lo);
}

// ---------------- merged recurrent weight pack: 4 matrices per level ----------------
__global__ __launch_bounds__(256) void pack_rec(
    const float* __restrict__ wgf, const float* __restrict__ wgb,
    const float* __restrict__ wcf, const float* __restrict__ wcb,
    uint4* __restrict__ RgH, uint4* __restrict__ RgL,
    uint4* __restrict__ RcH, uint4* __restrict__ RcL)
{
    int sel = blockIdx.y;
    const float* src; uint4 *dH, *dL; int N16, N;
    if (sel == 0)      { src = wgf; dH = RgH;        dL = RgL;        N16 = 16; N = 256; }
    else if (sel == 1) { src = wgb; dH = RgH + 4096; dL = RgL + 4096; N16 = 16; N = 256; }
    else if (sel == 2) { src = wcf; dH = RcH;        dL = RcL;        N16 = 8;  N = 128; }
    else               { src = wcb; dH = RcH + 2048; dL = RcL + 2048; N16 = 8;  N = 128; }
    int idx = blockIdx.x * 256 + threadIdx.x;
    if (idx >= N16 * 4 * 64) return;
    int lane = idx & 63;
    int g = idx >> 6;
    int nb = g / 4, kc = g - nb * 4;
    int m = lane & 15, quad = lane >> 4;
    int n = nb * 16 + m;
    int k0 = kc * 32 + quad * 8;
    unsigned short hi[8], lo[8];
#pragma unroll
    for (int j = 0; j < 8; ++j) {
        float x = src[(size_t)(k0 + j) * N + n];
        unsigned short h = f2bf(x);
        hi[j] = h;
        lo[j] = f2bf(x - bf2f(h));
    }
    dH[idx] = pack8(hi);
    dL[idx] = pack8(lo);
}

// ---------------- MFMA GEMM: C = A @ W + bias, split-bf16 3-product ----------------
__global__ __launch_bounds__(256) void mfma_gemm(
    const uint4* __restrict__ Ah, const uint4* __restrict__ Al,
    const uint4* __restrict__ Bh, const uint4* __restrict__ Bl,
    const float* __restrict__ bias, float* __restrict__ C,
    int KC, int ldc, int act)
{
    int tid = threadIdx.x;
    int lane = tid & 63;
    int w = tid >> 6;
    int wm = w >> 1, wn = w & 1;
    int quad = lane >> 4, m = lane & 15;
    int bm = blockIdx.x, bn = blockIdx.y;
    f32x4 acc[4][4];
#pragma unroll
    for (int i = 0; i < 4; ++i)
#pragma unroll
        for (int j = 0; j < 4; ++j) acc[i][j] = (f32x4){0.f, 0.f, 0.f, 0.f};

    size_t aBase[4], bBase[4];
#pragma unroll
    for (int i = 0; i < 4; ++i) {
        aBase[i] = ((size_t)(bm * 8 + wm * 4 + i) * KC) * 64 + quad * 16 + m;
        bBase[i] = ((size_t)(bn * 8 + wn * 4 + i) * KC) * 64 + quad * 16 + m;
    }
    for (int kc = 0; kc < KC; ++kc) {
        short8 ah[4], al[4], bh[4], bl[4];
#pragma unroll
        for (int i = 0; i < 4; ++i) {
            ah[i] = __builtin_bit_cast(short8, Ah[aBase[i]]);
            al[i] = __builtin_bit_cast(short8, Al[aBase[i]]);
            bh[i] = __builtin_bit_cast(short8, Bh[bBase[i]]);
            bl[i] = __builtin_bit_cast(short8, Bl[bBase[i]]);
            aBase[i] += 64; bBase[i] += 64;
        }
#pragma unroll
        for (int i = 0; i < 4; ++i)
#pragma unroll
            for (int j = 0; j < 4; ++j) {
                acc[i][j] = __builtin_amdgcn_mfma_f32_16x16x32_bf16(ah[i], bh[j], acc[i][j], 0, 0, 0);
                acc[i][j] = __builtin_amdgcn_mfma_f32_16x16x32_bf16(ah[i], bl[j], acc[i][j], 0, 0, 0);
                acc[i][j] = __builtin_amdgcn_mfma_f32_16x16x32_bf16(al[i], bh[j], acc[i][j], 0, 0, 0);
            }
    }
#pragma unroll
    for (int i = 0; i < 4; ++i) {
        int row0 = bm * 128 + wm * 64 + i * 16 + quad * 4;
#pragma unroll
        for (int j = 0; j < 4; ++j) {
            int col = bn * 128 + wn * 64 + j * 16 + m;
            float b = bias[col];
#pragma unroll
            for (int r = 0; r < 4; ++r) {
                float v = acc[i][j][r] + b;
                if (act) v = ftanh(v);
                C[(size_t)(row0 + r) * ldc + col] = v;
            }
        }
    }
}

// ---------------- MFMA BiGRU v3: 16 rows x 1 dir per block, bf16-mirrored state ----------------
// h kept fp32 (hs) AND pre-split bf16 A-frag mirrors (hfH/hfL) written during update;
// rh only as frag mirrors (rfH/rfL). Frag "build" = 2 ds_read_b128 per kc (ideal pattern).
__global__ __launch_bounds__(256) void bigru_mfma(
    const float* __restrict__ G,      // [nRows*T, 768] chunk-local
    const uint4* __restrict__ WgH, const uint4* __restrict__ WgL,  // [2 dirs][16 nt][4 kc][64]
    const uint4* __restrict__ WcH, const uint4* __restrict__ WcL,  // [2 dirs][8 nt][4 kc][64]
    const int* __restrict__ lens,
    float* __restrict__ outbuf,       // [nRows*T, 256] chunk-local (zeros at invalid)
    int rowOff, int T)
{
    __shared__ float hs[16][132];
    __shared__ float zs[16][132];
    __shared__ uint4 hfH[4][64], hfL[4][64];
    __shared__ uint4 rfH[4][64], rfL[4][64];
    __shared__ int Ls[16];

    int tid = threadIdx.x;
    int dir = blockIdx.x & 1;
    int rg0 = (blockIdx.x >> 1) * 16;
    int lane = tid & 63, w = tid >> 6;
    int quad = lane >> 4, mc = lane & 15;
    for (int i = tid; i < 16 * 132; i += 256) { (&hs[0][0])[i] = 0.f; }
    for (int i = tid; i < 256; i += 256) { hfH[0][i] = (uint4){0,0,0,0}; hfL[0][i] = (uint4){0,0,0,0}; }
    if (tid < 16) Ls[tid] = lens[rowOff + rg0 + tid];
    __syncthreads();
    const int goff = dir * 384;
    unsigned short* hfHu = (unsigned short*)hfH;
    unsigned short* hfLu = (unsigned short*)hfL;
    unsigned short* rfHu = (unsigned short*)rfH;
    unsigned short* rfLu = (unsigned short*)rfL;

    for (int t = 0; t < T; ++t) {
        int Lr[4], tir[4];
#pragma unroll
        for (int r = 0; r < 4; ++r) {
            int L = Ls[quad * 4 + r];
            Lr[r] = L;
            tir[r] = dir ? ((t < L) ? (L - 1 - t) : t) : t;
        }
        // prefetch G (consumed after MFMAs)
        float gG[4][4], gC[2][4];
#pragma unroll
        for (int r = 0; r < 4; ++r) {
            const float* gbase = &G[((size_t)(rg0 + quad * 4 + r) * T + tir[r]) * 768 + goff];
#pragma unroll
            for (int i = 0; i < 4; ++i) gG[i][r] = gbase[(w * 4 + i) * 16 + mc];
#pragma unroll
            for (int i = 0; i < 2; ++i) gC[i][r] = gbase[256 + (w * 2 + i) * 16 + mc];
        }
        // gates MFMA: wave handles n-tiles w*4..w*4+3 of 16
        f32x4 ga[4];
#pragma unroll
        for (int i = 0; i < 4; ++i) ga[i] = (f32x4){0.f, 0.f, 0.f, 0.f};
#pragma unroll
        for (int kc = 0; kc < 4; ++kc) {
            short8 ah = __builtin_bit_cast(short8, hfH[kc][lane]);
            short8 al = __builtin_bit_cast(short8, hfL[kc][lane]);
#pragma unroll
            for (int i = 0; i < 4; ++i) {
                size_t idx = (((size_t)(dir * 16 + w * 4 + i) * 4 + kc) << 6) + lane;
                short8 bh = __builtin_bit_cast(short8, WgH[idx]);
                short8 bl = __builtin_bit_cast(short8, WgL[idx]);
                ga[i] = __builtin_amdgcn_mfma_f32_16x16x32_bf16(ah, bh, ga[i], 0, 0, 0);
                ga[i] = __builtin_amdgcn_mfma_f32_16x16x32_bf16(ah, bl, ga[i], 0, 0, 0);
                ga[i] = __builtin_amdgcn_mfma_f32_16x16x32_bf16(al, bh, ga[i], 0, 0, 0);
            }
        }
        // gate elementwise: rh -> rf frags (u16), z -> zs
#pragma unroll
        for (int i = 0; i < 4; ++i) {
            int n = (w * 4 + i) * 16 + mc;
#pragma unroll
            for (int r = 0; r < 4; ++r) {
                int m = quad * 4 + r;
                float s = fsigmoid(ga[i][r] + gG[i][r]);
                if (n < 128) {
                    float rh = s * hs[m][n];
                    unsigned short hi = f2bf(rh);
                    int fi = ((((n >> 5) * 64) + (((n >> 3) & 3) * 16) + m) << 3) + (n & 7);
                    rfHu[fi] = hi;
                    rfLu[fi] = f2bf(rh - bf2f(hi));
                } else {
                    zs[m][n - 128] = s;
                }
            }
        }
        __syncthreads();
        // cand MFMA: wave handles n-tiles w*2..w*2+1 of 8
        f32x4 ca[2];
#pragma unroll
        for (int i = 0; i < 2; ++i) ca[i] = (f32x4){0.f, 0.f, 0.f, 0.f};
#pragma unroll
        for (int kc = 0; kc < 4; ++kc) {
            short8 ar = __builtin_bit_cast(short8, rfH[kc][lane]);
            short8 al = __builtin_bit_cast(short8, rfL[kc][lane]);
#pragma unroll
            for (int i = 0; i < 2; ++i) {
                size_t idx = (((size_t)(dir * 8 + w * 2 + i) * 4 + kc) << 6) + lane;
                short8 bh = __builtin_bit_cast(short8, WcH[idx]);
                short8 bl = __builtin_bit_cast(short8, WcL[idx]);
                ca[i] = __builtin_amdgcn_mfma_f32_16x16x32_bf16(ar, bh, ca[i], 0, 0, 0);
                ca[i] = __builtin_amdgcn_mfma_f32_16x16x32_bf16(ar, bl, ca[i], 0, 0, 0);
                ca[i] = __builtin_amdgcn_mfma_f32_16x16x32_bf16(al, bh, ca[i], 0, 0, 0);
            }
        }
        // update: h' = z*h + (1-z)*cand; refresh fp32 + bf16 mirrors; write out
#pragma unroll
        for (int i = 0; i < 2; ++i) {
            int n = (w * 2 + i) * 16 + mc;
            int fi0 = ((((n >> 5) * 64) + (((n >> 3) & 3) * 16)) << 3) + (n & 7);
#pragma unroll
            for (int r = 0; r < 4; ++r) {
                int m = quad * 4 + r;
                bool valid = (t < Lr[r]);
                float cd = ftanh(ca[i][r] + gC[i][r]);
                float z = zs[m][n];
                float h = hs[m][n];
                float hn = z * h + (1.f - z) * cd;
                float ov = valid ? hn : 0.f;
                if (valid) {
                    hs[m][n] = hn;
                    unsigned short hi = f2bf(hn);
                    int fi = fi0 + (m << 3);
                    hfHu[fi] = hi;
                    hfLu[fi] = f2bf(hn - bf2f(hi));
                }
                outbuf[((size_t)(rg0 + m) * T + tir[r]) * 256 + dir * 128 + n] = ov;
            }
        }
        __syncthreads();
    }
}

// ---------------- fused attention: proj MFMA + score + softmax + weighted sum ----------------
// one block per sequence; T <= 50; outv rows t>=L are zeros (bigru guarantees).
__global__ __launch_bounds__(256) void attn_fused(
    const float* __restrict__ outv,   // [n*T, 256]
    const uint4* __restrict__ WaH, const uint4* __restrict__ WaL,  // [8 nt][8 kc][64]
    const float* __restrict__ ba, const float* __restrict__ u,
    float* __restrict__ att_out,      // rows (attRowOff+n)*T
    float* __restrict__ vec,          // [n, 256]
    int T, int attRowOff)
{
    __shared__ float lowS[50][260];
    __shared__ float scoreS[64];
    __shared__ float attS[64];
    int n = blockIdx.x;
    int tid = threadIdx.x;
    int lane = tid & 63, w = tid >> 6;
    int quad = lane >> 4, mc = lane & 15;

    // stage low rows into LDS (coalesced float4)
    const float4* src4 = (const float4*)(outv + (size_t)n * T * 256);
    for (int idx = tid; idx < T * 64; idx += 256) {
        int row = idx >> 6, c4 = idx & 63;
        float4 v = src4[idx];
        *(float4*)&lowS[row][c4 * 4] = v;
    }
    __syncthreads();

    // proj = tanh(low @ wa + ba) for wave's 16-row tile; accumulate scores
    f32x4 acc[8];
#pragma unroll
    for (int j = 0; j < 8; ++j) acc[j] = (f32x4){0.f, 0.f, 0.f, 0.f};
    int rowA = w * 16 + mc;
    bool rowValid = rowA < T;
#pragma unroll
    for (int kc = 0; kc < 8; ++kc) {
        float v[8];
        if (rowValid) {
            const float* p = &lowS[rowA][kc * 32 + quad * 8];
#pragma unroll
            for (int j = 0; j < 8; ++j) v[j] = p[j];
        } else {
#pragma unroll
            for (int j = 0; j < 8; ++j) v[j] = 0.f;
        }
        short8 ah, al;
        cvt8(v, ah, al);
#pragma unroll
        for (int nt = 0; nt < 8; ++nt) {
            size_t idx = (((size_t)nt * 8 + kc) << 6) + lane;
            short8 bh = __builtin_bit_cast(short8, WaH[idx]);
            short8 bl = __builtin_bit_cast(short8, WaL[idx]);
            acc[nt] = __builtin_amdgcn_mfma_f32_16x16x32_bf16(ah, bh, acc[nt], 0, 0, 0);
            acc[nt] = __builtin_amdgcn_mfma_f32_16x16x32_bf16(ah, bl, acc[nt], 0, 0, 0);
            acc[nt] = __builtin_amdgcn_mfma_f32_16x16x32_bf16(al, bh, acc[nt], 0, 0, 0);
        }
    }
    // score partials: sc[r] = sum_nt tanh(acc + ba[col]) * u[col], col = nt*16+mc
    float sc[4] = {0.f, 0.f, 0.f, 0.f};
#pragma unroll
    for (int nt = 0; nt < 8; ++nt) {
        int col = nt * 16 + mc;
        float bb = ba[col], uu = u[col];
#pragma unroll
        for (int r = 0; r < 4; ++r)
            sc[r] += ftanh(acc[nt][r] + bb) * uu;
    }
    // reduce across the 16 col-lanes within each quad
#pragma unroll
    for (int off = 1; off < 16; off <<= 1) {
#pragma unroll
        for (int r = 0; r < 4; ++r) sc[r] += __shfl_xor(sc[r], off);
    }
    if (mc == 0) {
#pragma unroll
        for (int r = 0; r < 4; ++r) scoreS[w * 16 + quad * 4 + r] = sc[r];
    }
    __syncthreads();
    // softmax over rows 0..T-1 (wave 0; one lane per row)
    if (w == 0) {
        float s = (lane < T) ? scoreS[lane] : -3.402823466e38f;
        float m = s;
#pragma unroll
        for (int off = 1; off < 64; off <<= 1) m = fmaxf(m, __shfl_xor(m, off));
        float e = (lane < T) ? __expf(s - m) : 0.f;
        float sum = e;
#pragma unroll
        for (int off = 1; off < 64; off <<= 1) sum += __shfl_xor(sum, off);
        float att = e / sum;
        attS[lane] = att;
        if (lane < T) att_out[(size_t)(attRowOff + n) * T + lane] = att;
    }
    __syncthreads();
    // weighted sum: vec[hc] = sum_t att[t] * low[t][hc]
    float a = 0.f;
    for (int t = 0; t < T; ++t) a += attS[t] * lowS[t][tid];
    vec[(size_t)n * 256 + tid] = a;
}

// ---------------- head: logits, log-softmax, loss(+reg), predict, accuracy ----------------
__global__ __launch_bounds__(256) void head_kernel(
    const float* __restrict__ dvec, const float* __restrict__ wp, const float* __restrict__ bp,
    const int* __restrict__ y,
    const float* __restrict__ wa_l, const float* __restrict__ ba_l, const float* __restrict__ wa_h,
    const float* __restrict__ uw, const float* __restrict__ us,
    float* __restrict__ out)
{
    __shared__ float lg[64][10];
    __shared__ float red[256];
    int tid = threadIdx.x;
    for (int idx = tid; idx < 640; idx += 256) {
        int r = idx / 10, c = idx % 10;
        float a = bp[c];
        const float* dv = dvec + r * 256;
        for (int k = 0; k < 256; ++k) a += dv[k] * wp[k * 10 + c];
        lg[r][c] = a;
    }
    __syncthreads();
    float lossv = 0.f, corr = 0.f;
    if (tid < 64) {
        float m = lg[tid][0]; int arg = 0;
        for (int c = 1; c < 10; ++c) if (lg[tid][c] > m) { m = lg[tid][c]; arg = c; }
        float se = 0.f;
        for (int c = 0; c < 10; ++c) se += __expf(lg[tid][c] - m);
        float lse = m + __logf(se);
        int yy = y[tid];
        lossv = -(lg[tid][yy] - lse);
        corr = (yy == arg) ? 1.f : 0.f;
        out[1 + tid] = (float)arg;
    }
    float rs = 0.f;
    for (int i = tid; i < 32768; i += 256) {
        float v = wa_l[i]; rs += v * v;
        float w = wa_h[i]; rs += 2.f * w * w;
    }
    if (tid < 128) {
        float v1 = ba_l[tid], v2 = uw[tid], v3 = us[tid];
        rs += v1 * v1 + v2 * v2 + v3 * v3;
    }
    red[tid] = lossv; __syncthreads();
    for (int o = 128; o > 0; o >>= 1) { if (tid < o) red[tid] += red[tid + o]; __syncthreads(); }
    float totLoss = red[0]; __syncthreads();
    red[tid] = corr; __syncthreads();
    for (int o = 128; o > 0; o >>= 1) { if (tid < o) red[tid] += red[tid + o]; __syncthreads(); }
    float totCorr = red[0]; __syncthreads();
    red[tid] = rs; __syncthreads();
    for (int o = 128; o > 0; o >>= 1) { if (tid < o) red[tid] += red[tid + o]; __syncthreads(); }
    float totReg = red[0];
    if (tid == 0) {
        out[0] = totLoss / 64.f + 0.01f * totReg;
        out[65] = totCorr / 64.f;
    }
}

extern "C" void kernel_launch(void* const* d_in, const int* in_sizes, int n_in,
                              void* d_out, int out_size, void* d_ws, size_t ws_size,
                              hipStream_t stream)
{
    const float* X    = (const float*)d_in[0];
    const int*   y    = (const int*)d_in[1];
    const int*   slen = (const int*)d_in[2];
    const int*   dlen = (const int*)d_in[3];
    const float* wgf_l = (const float*)d_in[6];
    const float* bgf_l = (const float*)d_in[7];
    const float* wcf_l = (const float*)d_in[8];
    const float* bcf_l = (const float*)d_in[9];
    const float* wgb_l = (const float*)d_in[10];
    const float* bgb_l = (const float*)d_in[11];
    const float* wcb_l = (const float*)d_in[12];
    const float* bcb_l = (const float*)d_in[13];
    const float* wa_l  = (const float*)d_in[14];
    const float* ba_l  = (const float*)d_in[15];
    const float* wgf_h = (const float*)d_in[16];
    const float* bgf_h = (const float*)d_in[17];
    const float* wcf_h = (const float*)d_in[18];
    const float* bcf_h = (const float*)d_in[19];
    const float* wgb_h = (const float*)d_in[20];
    const float* bgb_h = (const float*)d_in[21];
    const float* wcb_h = (const float*)d_in[22];
    const float* bcb_h = (const float*)d_in[23];
    const float* wa_h  = (const float*)d_in[24];
    const float* ba_h  = (const float*)d_in[25];
    const float* uw    = (const float*)d_in[26];
    const float* us    = (const float*)d_in[27];
    const float* wp    = (const float*)d_in[28];
    const float* bp    = (const float*)d_in[29];
    float* out = (float*)d_out;

    // per-M1-row floats: G1 768 + low 256 + AXpack 224 = 1248; const ~5.2M floats
    int NCH = 1;
    while (NCH < 8) {
        size_t M1t = 128000ull / NCH;
        size_t needB = (M1t * 1248ull + 5200000ull) * 4ull;
        if (needB <= ws_size) break;
        NCH *= 2;
    }
    size_t nRows = 2560 / NCH;
    size_t M1 = nRows * 50;

    float* G1     = (float*)d_ws;            // M1*768
    float* low    = G1 + M1 * 768;           // M1*256
    float* AXf    = low + M1 * 256;          // M1*224
    float* sent   = AXf + M1 * 224;          // 655360
    float* Gs     = sent + 655360;           // 1966080
    float* high   = Gs + 1966080;            // 655360
    float* dvec   = high + 655360;           // 16384
    float* pSf    = dvec + 16384;            // 655360 (sent pack hi/lo)
    float* WpackL = pSf + 655360;            // 153600
    float* biasL  = WpackL + 153600;         // 768
    float* WLf    = biasL + 768;             // 172032
    float* WpackH = WLf + 172032;            // 196608
    float* biasH  = WpackH + 196608;         // 768
    float* WHf    = biasH + 768;             // 196608
    float* WaLf   = WHf + 196608;            // 32768
    float* WaHf   = WaLf + 32768;            // 32768
    float* RgLf   = WaHf + 32768;            // 65536
    float* RcLf   = RgLf + 65536;            // 32768
    float* RgHf   = RcLf + 32768;            // 65536
    float* RcHf   = RgHf + 65536;            // 32768

    uint4* AXh = (uint4*)AXf;           uint4* AXl = (uint4*)(AXf + M1 * 112);
    uint4* pSh = (uint4*)pSf;           uint4* pSl = (uint4*)(pSf + 327680);
    uint4* WLh = (uint4*)WLf;           uint4* WLl = (uint4*)(WLf + 86016);
    uint4* WHh = (uint4*)WHf;           uint4* WHl = (uint4*)(WHf + 98304);
    uint4* WaLh = (uint4*)WaLf;         uint4* WaLl = (uint4*)(WaLf + 16384);
    uint4* WaHh = (uint4*)WaHf;         uint4* WaHl = (uint4*)(WaHf + 16384);
    uint4* RgLH = (uint4*)RgLf;         uint4* RgLL = (uint4*)(RgLf + 32768);
    uint4* RcLH = (uint4*)RcLf;         uint4* RcLL = (uint4*)(RcLf + 16384);
    uint4* RgHH = (uint4*)RgHf;         uint4* RgHL = (uint4*)(RgHf + 32768);
    uint4* RcHH = (uint4*)RcHf;         uint4* RcHL = (uint4*)(RcHf + 16384);

    // ---- one-time weight packing ----
    pack_weights<<<600, 256, 0, stream>>>(wgf_l, bgf_l, wcf_l, bcf_l, wgb_l, bgb_l, wcb_l, bcb_l,
                                          WpackL, biasL, 200);
    pack_weights<<<768, 256, 0, stream>>>(wgf_h, bgf_h, wcf_h, bcf_h, wgb_h, bgb_h, wcb_h, bcb_h,
                                          WpackH, biasH, 256);
    pack_w_frag<<<84, 256, 0, stream>>>(WpackL, WLh, WLl, 48, 7, 200, 768);
    pack_w_frag<<<96, 256, 0, stream>>>(WpackH, WHh, WHl, 48, 8, 256, 768);
    pack_w_frag<<<16, 256, 0, stream>>>(wa_l, WaLh, WaLl, 8, 8, 256, 128);
    pack_w_frag<<<16, 256, 0, stream>>>(wa_h, WaHh, WaHl, 8, 8, 256, 128);
    pack_rec<<<dim3(16, 4), 256, 0, stream>>>(wgf_l + 200 * 256, wgb_l + 200 * 256,
                                              wcf_l + 200 * 128, wcb_l + 200 * 128,
                                              RgLH, RgLL, RcLH, RcLL);
    pack_rec<<<dim3(16, 4), 256, 0, stream>>>(wgf_h + 256 * 256, wgb_h + 256 * 256,
                                              wcf_h + 256 * 128, wcb_h + 256 * 128,
                                              RgHH, RgHL, RcHH, RcHL);

    for (int c = 0; c < NCH; ++c) {
        const float* Xc = X + (size_t)c * nRows * 50 * 200;
        int Mr16 = (int)(M1 / 16);
        pack_a_frag<<<(Mr16 * 7 * 64 + 255) / 256, 256, 0, stream>>>(Xc, AXh, AXl, Mr16, 7, 200);
        mfma_gemm<<<dim3((int)(M1 / 128), 6), 256, 0, stream>>>(AXh, AXl, WLh, WLl, biasL, G1, 7, 768, 0);
        bigru_mfma<<<(int)(nRows / 16) * 2, 256, 0, stream>>>(G1, RgLH, RgLL, RcLH, RcLL,
                                                              slen, low, (int)(c * nRows), 50);
        attn_fused<<<(int)nRows, 256, 0, stream>>>(low, WaLh, WaLl, ba_l, uw,
                                                   out + 66, sent + (size_t)c * nRows * 256, 50, (int)(c * nRows));
    }
    // ---- sentence level ----
    pack_a_frag<<<(160 * 8 * 64 + 255) / 256, 256, 0, stream>>>(sent, pSh, pSl, 160, 8, 256);
    mfma_gemm<<<dim3(20, 6), 256, 0, stream>>>(pSh, pSl, WHh, WHl, biasH, Gs, 8, 768, 0);
    bigru_mfma<<<8, 256, 0, stream>>>(Gs, RgHH, RgHL, RcHH, RcHL, dlen, high, 0, 40);
    attn_fused<<<64, 256, 0, stream>>>(high, WaHh, WaHl, ba_h, us, out + 128066, dvec, 40, 0);
    head_kernel<<<1, 256, 0, stream>>>(dvec, wp, bp, y, wa_l, ba_l, wa_h, uw, us, out);
}